// Round 12
// baseline (322.799 us; speedup 1.0000x reference)
//
#include <hip/hip_runtime.h>

// Problem constants (B=8, T=1, H=56, C=512, nh=8, d=64)
// Inputs: float32. Output: float32. ws intermediates: bf16 (+f32 m/l partials).
#define NH    8
#define DH    64
#define NTOK  3137      // 56*56+1
#define NOUT  785       // 28*28+1
#define CDIM  512
#define ROWS  6280      // 8*785
#define HO    28
#define HIN   56
#define NKT   13        // ceil(785/64) key tiles
#define RELD  55        // 2*(56//2)-1

typedef unsigned short u16;
typedef __attribute__((ext_vector_type(8))) short bf16x8;   // 8 bf16 = 4 VGPRs
typedef __attribute__((ext_vector_type(4))) float f32x4;    // MFMA C/D

__device__ __forceinline__ float b2f(u16 u) { return __uint_as_float(((unsigned)u) << 16); }
__device__ __forceinline__ u16 f2b(float f) {
  unsigned u = __float_as_uint(f);
  return (u16)((u + 0x7FFFu + ((u >> 16) & 1u)) >> 16);
}

// ---------------------------------------------------------------------------
// Kernel 1: depthwise 3x3 stride-2 pool + LayerNorm(64).
// 4 waves/block, one token per wave. z=0: q from x. z=1: k AND v from x_ref.
// ---------------------------------------------------------------------------
__global__ __launch_bounds__(256) void pool_ln_kernel(
    const float* __restrict__ x, const float* __restrict__ xr,
    const float* __restrict__ cwq, const float* __restrict__ cwk, const float* __restrict__ cwv,
    const float* __restrict__ gq, const float* __restrict__ bq,
    const float* __restrict__ gk, const float* __restrict__ bk,
    const float* __restrict__ gv, const float* __restrict__ bv,
    u16* __restrict__ Pq, u16* __restrict__ Pk, u16* __restrict__ Pv)
{
  int n     = blockIdx.x * 4 + (threadIdx.x >> 6);   // token
  int bh    = blockIdx.y;
  int which = blockIdx.z;                            // 0=q(x), 1=k+v(x_ref)
  if (n >= NOUT) return;                             // wave-uniform
  int b = bh >> 3, h = bh & 7;
  int di = threadIdx.x & 63;

  const float* src = (which == 0) ? x : xr;
  size_t srcbase = (size_t)b * NTOK * CDIM + (size_t)h * DH + di;
  size_t obase = (size_t)(b * NOUT + n) * CDIM + h * DH + di;

  float vq = 0.f, vk = 0.f;
  const float* cw0 = (which == 0) ? cwq : cwk;

  if (n == 0) {
    float t = src[srcbase];
    vq = t; vk = t;
  } else {
    int oy = (n - 1) / HO, ox = (n - 1) % HO;
#pragma unroll
    for (int ky = 0; ky < 3; ++ky) {
      int iy = oy * 2 - 1 + ky;
      if (iy < 0 || iy >= HIN) continue;
#pragma unroll
      for (int kx = 0; kx < 3; ++kx) {
        int ix = ox * 2 - 1 + kx;
        if (ix < 0 || ix >= HIN) continue;
        int tok = 1 + iy * HIN + ix;
        float t = src[srcbase + (size_t)tok * CDIM];
        vq += t * cw0[(ky * 3 + kx) * DH + di];
        if (which == 1) vk += t * cwv[(ky * 3 + kx) * DH + di];
      }
    }
  }

  {
    float s = vq, sq = vq * vq;
#pragma unroll
    for (int off = 32; off > 0; off >>= 1) {
      s  += __shfl_xor(s, off, 64);
      sq += __shfl_xor(sq, off, 64);
    }
    float mu  = s * (1.f / 64.f);
    float var = sq * (1.f / 64.f) - mu * mu;
    const float* g  = (which == 0) ? gq : gk;
    const float* be = (which == 0) ? bq : bk;
    float o = (vq - mu) * rsqrtf(var + 1e-5f) * g[di] + be[di];
    ((which == 0) ? Pq : Pk)[obase] = f2b(o);
  }
  if (which == 1) {
    float s = vk, sq = vk * vk;
#pragma unroll
    for (int off = 32; off > 0; off >>= 1) {
      s  += __shfl_xor(s, off, 64);
      sq += __shfl_xor(sq, off, 64);
    }
    float mu  = s * (1.f / 64.f);
    float var = sq * (1.f / 64.f) - mu * mu;
    float o = (vk - mu) * rsqrtf(var + 1e-5f) * gv[di] + bv[di];
    Pv[obase] = f2b(o);
  }
}

// ---------------------------------------------------------------------------
// Kernel 2: convert the four 512x512 f32 weight matrices to bf16 (packed).
// ---------------------------------------------------------------------------
__global__ __launch_bounds__(256) void wcvt_kernel(
    const float* __restrict__ W0, const float* __restrict__ W1,
    const float* __restrict__ W2, const float* __restrict__ W3,
    u16* __restrict__ out)
{
  int idx = blockIdx.x * blockDim.x + threadIdx.x;
  const int per = CDIM * CDIM / 4;
  int mat = idx / per, off = (idx - mat * per) * 4;
  const float* src = (mat == 0) ? W0 : (mat == 1) ? W1 : (mat == 2) ? W2 : W3;
  float4 v = *(const float4*)(src + off);
  ushort4 o;
  o.x = f2b(v.x); o.y = f2b(v.y); o.z = f2b(v.z); o.w = f2b(v.w);
  *(ushort4*)(out + (size_t)mat * (CDIM * CDIM) + off) = o;
}

// ---------------------------------------------------------------------------
// Kernel 3: rel_pos f32 (55x64) -> bf16 padded [64][64] (rows >=55 zero).
// ---------------------------------------------------------------------------
__global__ __launch_bounds__(256) void rcvt_kernel(
    const float* __restrict__ rph, const float* __restrict__ rpw,
    u16* __restrict__ Rhb, u16* __restrict__ Rwb)
{
  int idx = blockIdx.x * blockDim.x + threadIdx.x;
  if (idx >= 64 * 64) return;
  int r = idx >> 6, d = idx & 63;
  Rhb[idx] = (r < RELD) ? f2b(rph[r * DH + d]) : 0;
  Rwb[idx] = (r < RELD) ? f2b(rpw[r * DH + d]) : 0;
}

// ---------------------------------------------------------------------------
// Kernel 4a: batched MFMA GEMM for q/k/v. Output bf16 (b,h,n,d).
// ---------------------------------------------------------------------------
__global__ __launch_bounds__(256) void mgemm3_kernel(
    const u16* __restrict__ Xq, const u16* __restrict__ Xk, const u16* __restrict__ Xv,
    const u16* __restrict__ Wb, const float* __restrict__ bq,
    const float* __restrict__ bk, const float* __restrict__ bv,
    u16* __restrict__ Yq, u16* __restrict__ Yk, u16* __restrict__ Yv)
{
  int z = blockIdx.z;
  const u16* X = (z == 0) ? Xq : (z == 1) ? Xk : Xv;
  const u16* W = Wb + (size_t)z * CDIM * CDIM;
  const float* bias = (z == 0) ? bq : (z == 1) ? bk : bv;
  u16* Y = (z == 0) ? Yq : (z == 1) ? Yk : Yv;

  int tid = threadIdx.x;
  int w = tid >> 6, lane = tid & 63, l15 = lane & 15, lg = lane >> 4;
  int m0 = blockIdx.x * 128 + (w >> 1) * 64;
  int n0 = blockIdx.y * 128 + (w & 1) * 64;

  f32x4 acc[4][4] = {};
  float bs[4];
#pragma unroll
  for (int nf = 0; nf < 4; ++nf) bs[nf] = bias[n0 + nf * 16 + l15];

  for (int k0 = 0; k0 < CDIM; k0 += 32) {
    bf16x8 a[4], b[4];
#pragma unroll
    for (int mf = 0; mf < 4; ++mf) {
      int r = m0 + mf * 16 + l15;
      if (r > ROWS - 1) r = ROWS - 1;
      a[mf] = *(const bf16x8*)(X + (size_t)r * CDIM + k0 + lg * 8);
    }
#pragma unroll
    for (int nf = 0; nf < 4; ++nf) {
      int co = n0 + nf * 16 + l15;
      b[nf] = *(const bf16x8*)(W + (size_t)co * CDIM + k0 + lg * 8);
    }
#pragma unroll
    for (int mf = 0; mf < 4; ++mf)
#pragma unroll
      for (int nf = 0; nf < 4; ++nf)
        acc[mf][nf] = __builtin_amdgcn_mfma_f32_16x16x32_bf16(a[mf], b[nf], acc[mf][nf], 0, 0, 0);
  }

#pragma unroll
  for (int mf = 0; mf < 4; ++mf) {
#pragma unroll
    for (int j = 0; j < 4; ++j) {
      int r = m0 + mf * 16 + lg * 4 + j;
      if (r >= ROWS) continue;
      int bb = r / NOUT, n = r % NOUT;
#pragma unroll
      for (int nf = 0; nf < 4; ++nf) {
        int co = n0 + nf * 16 + l15;
        float v = acc[mf][nf][j] + bs[nf];
        Y[(((size_t)bb * NH + (co >> 6)) * NOUT + n) * DH + (co & 63)] = f2b(v);
      }
    }
  }
}

// ---------------------------------------------------------------------------
// Kernel 4b: proj MFMA GEMM -> f32 row-major d_out.
// ---------------------------------------------------------------------------
__global__ __launch_bounds__(256) void mgemm_proj_kernel(
    const u16* __restrict__ X, const u16* __restrict__ Wb, const float* __restrict__ bias,
    float* __restrict__ Y)
{
  int tid = threadIdx.x;
  int w = tid >> 6, lane = tid & 63, l15 = lane & 15, lg = lane >> 4;
  int m0 = blockIdx.x * 128 + (w >> 1) * 64;
  int n0 = blockIdx.y * 128 + (w & 1) * 64;

  f32x4 acc[4][4] = {};
  float bs[4];
#pragma unroll
  for (int nf = 0; nf < 4; ++nf) bs[nf] = bias[n0 + nf * 16 + l15];

  for (int k0 = 0; k0 < CDIM; k0 += 32) {
    bf16x8 a[4], b[4];
#pragma unroll
    for (int mf = 0; mf < 4; ++mf) {
      int r = m0 + mf * 16 + l15;
      if (r > ROWS - 1) r = ROWS - 1;
      a[mf] = *(const bf16x8*)(X + (size_t)r * CDIM + k0 + lg * 8);
    }
#pragma unroll
    for (int nf = 0; nf < 4; ++nf) {
      int co = n0 + nf * 16 + l15;
      b[nf] = *(const bf16x8*)(Wb + (size_t)co * CDIM + k0 + lg * 8);
    }
#pragma unroll
    for (int mf = 0; mf < 4; ++mf)
#pragma unroll
      for (int nf = 0; nf < 4; ++nf)
        acc[mf][nf] = __builtin_amdgcn_mfma_f32_16x16x32_bf16(a[mf], b[nf], acc[mf][nf], 0, 0, 0);
  }

#pragma unroll
  for (int mf = 0; mf < 4; ++mf) {
#pragma unroll
    for (int j = 0; j < 4; ++j) {
      int r = m0 + mf * 16 + lg * 4 + j;
      if (r >= ROWS) continue;
#pragma unroll
      for (int nf = 0; nf < 4; ++nf) {
        int co = n0 + nf * 16 + l15;
        Y[(size_t)r * CDIM + co] = acc[mf][nf][j] + bs[nf];
      }
    }
  }
}

// ---------------------------------------------------------------------------
// Kernel 5: flash attention, split-K x2 (half 0: tiles 0-6, half 1: 7-12).
// LDS 31.5 KB -> 5 blocks/CU. Single-buffer Vs with register V prefetch.
// Writes unnormalized O partials (bf16) + per-row m/l (f32).
// ---------------------------------------------------------------------------
__global__ __launch_bounds__(256, 5) void fattn_kernel(
    const u16* __restrict__ Q, const u16* __restrict__ K, const u16* __restrict__ V,
    const u16* __restrict__ Rhb, const u16* __restrict__ Rwb,
    u16* __restrict__ PO, float* __restrict__ PML)
{
  __shared__ u16 Vs[64][64];        // [d][k] XOR-swizzled           8192 B
  __shared__ u16 Ps[4][16][72];     // per-wave P bounce             9216 B
  __shared__ u16 relh[64][RELD];    // G_h[q][r]                     7040 B
  __shared__ u16 relw[64][RELD];    //                               7040 B

  // XCD swizzle: 1664 blocks = 8 * 208; consecutive nbid share bh.
  int bid = blockIdx.x;
  int nbid = (bid & 7) * 208 + (bid >> 3);
  int bh = nbid / 26;
  int r26 = nbid % 26;
  int qt = r26 >> 1, half = r26 & 1;
  int t0 = half ? 7 : 0, t1 = half ? NKT : 7;

  int tid = threadIdx.x;
  int w = tid >> 6, lane = tid & 63, l15 = lane & 15, lg = lane >> 4;
  size_t base = (size_t)bh * NOUT * DH;
  int q0 = qt * 64;

  int vkey_l = tid & 63;
  int vd0 = (tid >> 6) * 16;

  // ---- Q A-fragments direct from global ----
  int qrow_qi = min(q0 + w * 16 + l15, NOUT - 1);
  const u16* qp = Q + base + (size_t)qrow_qi * DH + lg * 8;
  bf16x8 qa0 = *(const bf16x8*)(qp);
  bf16x8 qa1 = *(const bf16x8*)(qp + 32);

  // ---- prefetch V tile t0 into registers ----
  bf16x8 nv0, nv1;
  {
    int key = min(t0 * 64 + vkey_l, NOUT - 1);
    const u16* vp = V + base + (size_t)key * DH + vd0;
    nv0 = *(const bf16x8*)(vp);
    nv1 = *(const bf16x8*)(vp + 8);
  }

  // ---- rel-pos tables via MFMA (wave-private rows) ----
#pragma unroll
  for (int nf = 0; nf < 4; ++nf) {
    int rr = nf * 16 + l15;
    const u16* hp = Rhb + rr * 64 + lg * 8;
    bf16x8 hb0 = *(const bf16x8*)(hp);
    bf16x8 hb1 = *(const bf16x8*)(hp + 32);
    f32x4 ah = {};
    ah = __builtin_amdgcn_mfma_f32_16x16x32_bf16(qa0, hb0, ah, 0, 0, 0);
    ah = __builtin_amdgcn_mfma_f32_16x16x32_bf16(qa1, hb1, ah, 0, 0, 0);
    const u16* wp = Rwb + rr * 64 + lg * 8;
    bf16x8 wb0 = *(const bf16x8*)(wp);
    bf16x8 wb1 = *(const bf16x8*)(wp + 32);
    f32x4 aw = {};
    aw = __builtin_amdgcn_mfma_f32_16x16x32_bf16(qa0, wb0, aw, 0, 0, 0);
    aw = __builtin_amdgcn_mfma_f32_16x16x32_bf16(qa1, wb1, aw, 0, 0, 0);
    if (rr < RELD) {
#pragma unroll
      for (int j = 0; j < 4; ++j) {
        relh[w * 16 + lg * 4 + j][rr] = f2b(ah[j]);
        relw[w * 16 + lg * 4 + j][rr] = f2b(aw[j]);
      }
    }
  }

  // ---- per-j query geometry ----
  int qy_j[4], qx_j[4];
  bool qv_j[4];
#pragma unroll
  for (int j = 0; j < 4; ++j) {
    int qi = q0 + w * 16 + lg * 4 + j;
    qv_j[j] = (qi >= 1);
    int qm1 = qi - 1;
    qy_j[j] = qm1 / HO;
    qx_j[j] = qm1 % HO;
  }

  // ---- incremental key geometry per sub (start at tile t0) ----
  int kyr[4], kxr[4];
#pragma unroll
  for (int sub = 0; sub < 4; ++sub) {
    int km1 = t0 * 64 + sub * 16 + l15 - 1;   // -1 only for (t0=0,sub=0,l15=0): unused
    kyr[sub] = km1 / HO;
    kxr[sub] = km1 % HO;
  }

  f32x4 o0 = {}, o1 = {}, o2 = {}, o3 = {};
  float mrow[4], lrow[4];
#pragma unroll
  for (int j = 0; j < 4; ++j) { mrow[j] = -1e30f; lrow[j] = 0.f; }

  for (int t = t0; t < t1; ++t) {
    int k0 = t * 64;
    __syncthreads();   // prev PV reads of Vs done

    // ---- stage Vs from prefetched registers (swizzled) ----
#pragma unroll
    for (int i = 0; i < 8; ++i) {
      int d = vd0 + i;
      Vs[d][((((vkey_l >> 3) ^ (d & 7)) << 3) | (vkey_l & 7))] = (u16)nv0[i];
    }
#pragma unroll
    for (int i = 0; i < 8; ++i) {
      int d = vd0 + 8 + i;
      Vs[d][((((vkey_l >> 3) ^ (d & 7)) << 3) | (vkey_l & 7))] = (u16)nv1[i];
    }
    __syncthreads();   // Vs ready

    // ---- issue next V tile's loads (latency hides under compute) ----
    if (t + 1 < t1) {
      int key = min(k0 + 64 + vkey_l, NOUT - 1);
      const u16* vp = V + base + (size_t)key * DH + vd0;
      nv0 = *(const bf16x8*)(vp);
      nv1 = *(const bf16x8*)(vp + 8);
    }

    // ---- K fragment loads ----
    bf16x8 kb[4][2];
#pragma unroll
    for (int sub = 0; sub < 4; ++sub) {
      int key = k0 + sub * 16 + l15;
      int keff = min(key, NOUT - 1);
      const u16* kp = K + base + (size_t)keff * DH + lg * 8;
      kb[sub][0] = *(const bf16x8*)(kp);
      kb[sub][1] = *(const bf16x8*)(kp + 32);
    }

    // ---- S = scale*Q.K^T + bias ----
    f32x4 s[4];
#pragma unroll
    for (int sub = 0; sub < 4; ++sub) {
      int key = k0 + sub * 16 + l15;
      f32x4 acc = {};
      acc = __builtin_amdgcn_mfma_f32_16x16x32_bf16(qa0, kb[sub][0], acc, 0, 0, 0);
      acc = __builtin_amdgcn_mfma_f32_16x16x32_bf16(qa1, kb[sub][1], acc, 0, 0, 0);
      bool kv = key < NOUT;
      int ky = kyr[sub], kx = kxr[sub];
#pragma unroll
      for (int j = 0; j < 4; ++j) {
        float v = acc[j] * 0.125f;
        if (key >= 1 && kv && qv_j[j]) {
          int ql = w * 16 + lg * 4 + j;
          v += b2f(relh[ql][qy_j[j] - ky + 27]) + b2f(relw[ql][qx_j[j] - kx + 27]);
        }
        if (!kv) v = -1e30f;
        s[sub][j] = v;
      }
    }

    // ---- advance key geometry (+64 keys = +2 rows +8 cols, carry) ----
#pragma unroll
    for (int sub = 0; sub < 4; ++sub) {
      kxr[sub] += 8; kyr[sub] += 2;
      if (kxr[sub] >= HO) { kxr[sub] -= HO; kyr[sub] += 1; }
    }

    // ---- online softmax ----
    float alpha[4];
#pragma unroll
    for (int j = 0; j < 4; ++j) {
      float lm = fmaxf(fmaxf(s[0][j], s[1][j]), fmaxf(s[2][j], s[3][j]));
      lm = fmaxf(lm, __shfl_xor(lm, 1));
      lm = fmaxf(lm, __shfl_xor(lm, 2));
      lm = fmaxf(lm, __shfl_xor(lm, 4));
      lm = fmaxf(lm, __shfl_xor(lm, 8));
      float mnew = fmaxf(mrow[j], lm);
      alpha[j] = __expf(mrow[j] - mnew);
      mrow[j] = mnew;
      float ps = 0.f;
#pragma unroll
      for (int sub = 0; sub < 4; ++sub) {
        float pv = __expf(s[sub][j] - mnew);
        s[sub][j] = pv;
        ps += pv;
      }
      ps += __shfl_xor(ps, 1);
      ps += __shfl_xor(ps, 2);
      ps += __shfl_xor(ps, 4);
      ps += __shfl_xor(ps, 8);
      lrow[j] = lrow[j] * alpha[j] + ps;
    }

    // ---- rescale O, bounce P (wave-private) ----
#pragma unroll
    for (int j = 0; j < 4; ++j) {
      o0[j] *= alpha[j]; o1[j] *= alpha[j]; o2[j] *= alpha[j]; o3[j] *= alpha[j];
      Ps[w][lg * 4 + j][ 0 + l15] = f2b(s[0][j]);
      Ps[w][lg * 4 + j][16 + l15] = f2b(s[1][j]);
      Ps[w][lg * 4 + j][32 + l15] = f2b(s[2][j]);
      Ps[w][lg * 4 + j][48 + l15] = f2b(s[3][j]);
    }

    // ---- O += P.V ----
    bf16x8 pa0 = *(const bf16x8*)&Ps[w][l15][lg * 8];
    bf16x8 pa1 = *(const bf16x8*)&Ps[w][l15][32 + lg * 8];
    {
      int r = 0 + l15;
      bf16x8 vb0 = *(const bf16x8*)&Vs[r][((lg ^ (r & 7)) << 3)];
      bf16x8 vb1 = *(const bf16x8*)&Vs[r][(((4 + lg) ^ (r & 7)) << 3)];
      o0 = __builtin_amdgcn_mfma_f32_16x16x32_bf16(pa0, vb0, o0, 0, 0, 0);
      o0 = __builtin_amdgcn_mfma_f32_16x16x32_bf16(pa1, vb1, o0, 0, 0, 0);
    }
    {
      int r = 16 + l15;
      bf16x8 vb0 = *(const bf16x8*)&Vs[r][((lg ^ (r & 7)) << 3)];
      bf16x8 vb1 = *(const bf16x8*)&Vs[r][(((4 + lg) ^ (r & 7)) << 3)];
      o1 = __builtin_amdgcn_mfma_f32_16x16x32_bf16(pa0, vb0, o1, 0, 0, 0);
      o1 = __builtin_amdgcn_mfma_f32_16x16x32_bf16(pa1, vb1, o1, 0, 0, 0);
    }
    {
      int r = 32 + l15;
      bf16x8 vb0 = *(const bf16x8*)&Vs[r][((lg ^ (r & 7)) << 3)];
      bf16x8 vb1 = *(const bf16x8*)&Vs[r][(((4 + lg) ^ (r & 7)) << 3)];
      o2 = __builtin_amdgcn_mfma_f32_16x16x32_bf16(pa0, vb0, o2, 0, 0, 0);
      o2 = __builtin_amdgcn_mfma_f32_16x16x32_bf16(pa1, vb1, o2, 0, 0, 0);
    }
    {
      int r = 48 + l15;
      bf16x8 vb0 = *(const bf16x8*)&Vs[r][((lg ^ (r & 7)) << 3)];
      bf16x8 vb1 = *(const bf16x8*)&Vs[r][(((4 + lg) ^ (r & 7)) << 3)];
      o3 = __builtin_amdgcn_mfma_f32_16x16x32_bf16(pa0, vb0, o3, 0, 0, 0);
      o3 = __builtin_amdgcn_mfma_f32_16x16x32_bf16(pa1, vb1, o3, 0, 0, 0);
    }
  }

  // ---- epilogue: write partials (unnormalized O, m, l) ----
  u16* oP = PO + (((size_t)(half * 64 + bh) * NKT + qt) << 12);
  float* mlP = PML + (((size_t)(half * 64 + bh) * NKT + qt) << 7);
#pragma unroll
  for (int j = 0; j < 4; ++j) {
    int ql = w * 16 + lg * 4 + j;
    if (l15 == 0) { mlP[ql] = mrow[j]; mlP[64 + ql] = lrow[j]; }
    size_t ob = (size_t)ql * 64;
    oP[ob +  0 + l15] = f2b(o0[j]);
    oP[ob + 16 + l15] = f2b(o1[j]);
    oP[ob + 32 + l15] = f2b(o2[j]);
    oP[ob + 48 + l15] = f2b(o3[j]);
  }
}

// ---------------------------------------------------------------------------
// Kernel 6: combine split-K partials: merge, normalize, residual, store.
// Grid (NKT, 64), 256 threads: thread = (q = tid>>2, 16 d's).
// ---------------------------------------------------------------------------
__global__ __launch_bounds__(256) void fcomb_kernel(
    const u16* __restrict__ PO, const float* __restrict__ PML,
    const u16* __restrict__ Q, u16* __restrict__ Oout)
{
  int qt = blockIdx.x, bh = blockIdx.y;
  int tid = threadIdx.x;
  int q = tid >> 2, d0 = (tid & 3) * 16;
  int qi = qt * 64 + q;
  if (qi >= NOUT) return;

  size_t idx0 = (size_t)bh * NKT + qt;
  size_t idx1 = (size_t)(64 + bh) * NKT + qt;
  const float* ml0 = PML + (idx0 << 7);
  const float* ml1 = PML + (idx1 << 7);
  float m0 = ml0[q], l0 = ml0[64 + q];
  float m1 = ml1[q], l1 = ml1[64 + q];
  float m = fmaxf(m0, m1);
  float a0 = __expf(m0 - m), a1 = __expf(m1 - m);
  float inv = 1.f / (l0 * a0 + l1 * a1);

  const u16* o0p = PO + (idx0 << 12) + (size_t)q * 64 + d0;
  const u16* o1p = PO + (idx1 << 12) + (size_t)q * 64 + d0;
  const u16* qp  = Q + (size_t)bh * NOUT * DH + (size_t)qi * DH + d0;
  int b = bh >> 3, h = bh & 7;
  u16* op = Oout + ((size_t)(b * NOUT) + qi) * CDIM + h * DH + d0;
#pragma unroll
  for (int i = 0; i < 16; ++i) {
    float o = (b2f(o0p[i]) * a0 + b2f(o1p[i]) * a1) * inv;
    if (qi > 0) o += b2f(qp[i]);
    op[i] = f2b(o);
  }
}

// ---------------------------------------------------------------------------
// ws layout (u16 units), total ~42.3 MB:
//   s0..s3    : 4 x PSZ
//   PO        : 2 x OSZ   (split-K O partials, bf16)
//   PML       : 2 x MLSZ f32 (= 4*MLSZ u16)
//   Wb        : 4 x WSZ ; Rhb/Rwb : 2 x 4096
// d_out (2 x PSZ u16 capacity): qb1 = Q, qb2 = Pq scratch.
// Schedule: pool: Pq->qb2, Pk->s0, Pv->s1
//           mgemm3: qb2->qb1(Q), s0->s2(K), s1->s3(V)
//           fattn:  (qb1,s2,s3) -> PO,PML
//           fcomb:  (PO,PML,qb1) -> s0
//           proj:   s0 -> d_out (f32)
// ---------------------------------------------------------------------------
extern "C" void kernel_launch(void* const* d_in, const int* in_sizes, int n_in,
                              void* d_out, int out_size, void* d_ws, size_t ws_size,
                              hipStream_t stream) {
  const float* x     = (const float*)d_in[0];
  const float* xr    = (const float*)d_in[1];
  const float* wq    = (const float*)d_in[2];
  const float* bq    = (const float*)d_in[3];
  const float* wk    = (const float*)d_in[4];
  const float* bk    = (const float*)d_in[5];
  const float* wv    = (const float*)d_in[6];
  const float* bv    = (const float*)d_in[7];
  const float* wpj   = (const float*)d_in[8];
  const float* bpj   = (const float*)d_in[9];
  const float* cwq   = (const float*)d_in[10];
  const float* cwk   = (const float*)d_in[11];
  const float* cwv   = (const float*)d_in[12];
  const float* gq    = (const float*)d_in[13];
  const float* lbq   = (const float*)d_in[14];
  const float* gk    = (const float*)d_in[15];
  const float* lbk   = (const float*)d_in[16];
  const float* gv    = (const float*)d_in[17];
  const float* lbv   = (const float*)d_in[18];
  const float* rph   = (const float*)d_in[19];
  const float* rpw   = (const float*)d_in[20];
  (void)in_sizes; (void)n_in; (void)out_size; (void)ws_size;

  u16* ws = (u16*)d_ws;
  const size_t PSZ = (size_t)ROWS * CDIM;            // 3,215,360
  const size_t WSZ = (size_t)CDIM * CDIM;            // 262,144
  const size_t OSZ = (size_t)64 * NKT * 64 * 64;     // 3,407,872
  const size_t MLSZ = (size_t)64 * NKT * 128;        // 106,496 (f32)
  u16* s0 = ws + 0 * PSZ;
  u16* s1 = ws + 1 * PSZ;
  u16* s2 = ws + 2 * PSZ;
  u16* s3 = ws + 3 * PSZ;
  u16* PO = ws + 4 * PSZ;
  float* PML = (float*)(ws + 4 * PSZ + 2 * OSZ);
  u16* Wb  = ws + 4 * PSZ + 2 * OSZ + 4 * MLSZ;
  u16* Rhb = Wb + 4 * WSZ;
  u16* Rwb = Rhb + 64 * 64;
  u16* qb1 = (u16*)d_out;
  u16* qb2 = qb1 + PSZ;

  // 1) pool + layernorm: Pq->qb2, Pk->s0, Pv->s1
  pool_ln_kernel<<<dim3((NOUT + 3) / 4, 64, 2), 256, 0, stream>>>(
      x, xr, cwq, cwk, cwv, gq, lbq, gk, lbk, gv, lbv, qb2, s0, s1);

  // 2) weights + rel_pos -> bf16
  wcvt_kernel<<<(4 * CDIM * CDIM / 4 + 255) / 256, 256, 0, stream>>>(wq, wk, wv, wpj, Wb);
  rcvt_kernel<<<16, 256, 0, stream>>>(rph, rpw, Rhb, Rwb);

  // 3) q/k/v projections: q: qb2->qb1, k: s0->s2, v: s1->s3
  dim3 g3((ROWS + 127) / 128, CDIM / 128, 3);
  mgemm3_kernel<<<g3, 256, 0, stream>>>(qb2, s0, s1, Wb, bq, bk, bv, qb1, s2, s3);

  // 4) attention split-K -> partials
  fattn_kernel<<<NKT * 64 * 2, 256, 0, stream>>>(qb1, s2, s3, Rhb, Rwb, PO, PML);

  // 5) combine -> s0
  fcomb_kernel<<<dim3(NKT, 64), 256, 0, stream>>>(PO, PML, qb1, s0);

  // 6) output projection -> f32 d_out
  dim3 ggrid((ROWS + 127) / 128, CDIM / 128);
  mgemm_proj_kernel<<<ggrid, 256, 0, stream>>>(s0, Wb + 3 * WSZ, bpj, (float*)d_out);
}

// Round 13
// 218.280 us; speedup vs baseline: 1.4788x; 1.4788x over previous
//
#include <hip/hip_runtime.h>

// Problem constants (B=8, T=1, H=56, C=512, nh=8, d=64)
// Inputs: float32. Output: float32. ws intermediates: bf16.
#define NH    8
#define DH    64
#define NTOK  3137      // 56*56+1
#define NOUT  785       // 28*28+1
#define CDIM  512
#define ROWS  6280      // 8*785
#define HO    28
#define HIN   56
#define NKT   13        // ceil(785/64) key tiles
#define RELD  55        // 2*(56//2)-1

typedef unsigned short u16;
typedef __attribute__((ext_vector_type(8))) short bf16x8;   // 8 bf16 = 4 VGPRs
typedef __attribute__((ext_vector_type(4))) float f32x4;    // MFMA C/D

__device__ __forceinline__ float b2f(u16 u) { return __uint_as_float(((unsigned)u) << 16); }
__device__ __forceinline__ u16 f2b(float f) {
  unsigned u = __float_as_uint(f);
  return (u16)((u + 0x7FFFu + ((u >> 16) & 1u)) >> 16);
}

// ---------------------------------------------------------------------------
// Kernel 1: depthwise 3x3 stride-2 pool + LayerNorm(64).
// 4 waves/block, one token per wave. z=0: q from x. z=1: k AND v from x_ref.
// ---------------------------------------------------------------------------
__global__ __launch_bounds__(256) void pool_ln_kernel(
    const float* __restrict__ x, const float* __restrict__ xr,
    const float* __restrict__ cwq, const float* __restrict__ cwk, const float* __restrict__ cwv,
    const float* __restrict__ gq, const float* __restrict__ bq,
    const float* __restrict__ gk, const float* __restrict__ bk,
    const float* __restrict__ gv, const float* __restrict__ bv,
    u16* __restrict__ Pq, u16* __restrict__ Pk, u16* __restrict__ Pv)
{
  int n     = blockIdx.x * 4 + (threadIdx.x >> 6);   // token
  int bh    = blockIdx.y;
  int which = blockIdx.z;                            // 0=q(x), 1=k+v(x_ref)
  if (n >= NOUT) return;                             // wave-uniform
  int b = bh >> 3, h = bh & 7;
  int di = threadIdx.x & 63;

  const float* src = (which == 0) ? x : xr;
  size_t srcbase = (size_t)b * NTOK * CDIM + (size_t)h * DH + di;
  size_t obase = (size_t)(b * NOUT + n) * CDIM + h * DH + di;

  float vq = 0.f, vk = 0.f;
  const float* cw0 = (which == 0) ? cwq : cwk;

  if (n == 0) {
    float t = src[srcbase];
    vq = t; vk = t;
  } else {
    int oy = (n - 1) / HO, ox = (n - 1) % HO;
#pragma unroll
    for (int ky = 0; ky < 3; ++ky) {
      int iy = oy * 2 - 1 + ky;
      if (iy < 0 || iy >= HIN) continue;
#pragma unroll
      for (int kx = 0; kx < 3; ++kx) {
        int ix = ox * 2 - 1 + kx;
        if (ix < 0 || ix >= HIN) continue;
        int tok = 1 + iy * HIN + ix;
        float t = src[srcbase + (size_t)tok * CDIM];
        vq += t * cw0[(ky * 3 + kx) * DH + di];
        if (which == 1) vk += t * cwv[(ky * 3 + kx) * DH + di];
      }
    }
  }

  {
    float s = vq, sq = vq * vq;
#pragma unroll
    for (int off = 32; off > 0; off >>= 1) {
      s  += __shfl_xor(s, off, 64);
      sq += __shfl_xor(sq, off, 64);
    }
    float mu  = s * (1.f / 64.f);
    float var = sq * (1.f / 64.f) - mu * mu;
    const float* g  = (which == 0) ? gq : gk;
    const float* be = (which == 0) ? bq : bk;
    float o = (vq - mu) * rsqrtf(var + 1e-5f) * g[di] + be[di];
    ((which == 0) ? Pq : Pk)[obase] = f2b(o);
  }
  if (which == 1) {
    float s = vk, sq = vk * vk;
#pragma unroll
    for (int off = 32; off > 0; off >>= 1) {
      s  += __shfl_xor(s, off, 64);
      sq += __shfl_xor(sq, off, 64);
    }
    float mu  = s * (1.f / 64.f);
    float var = sq * (1.f / 64.f) - mu * mu;
    float o = (vk - mu) * rsqrtf(var + 1e-5f) * gv[di] + bv[di];
    Pv[obase] = f2b(o);
  }
}

// ---------------------------------------------------------------------------
// Kernel 2: convert the four 512x512 f32 weight matrices to bf16 (packed).
// ---------------------------------------------------------------------------
__global__ __launch_bounds__(256) void wcvt_kernel(
    const float* __restrict__ W0, const float* __restrict__ W1,
    const float* __restrict__ W2, const float* __restrict__ W3,
    u16* __restrict__ out)
{
  int idx = blockIdx.x * blockDim.x + threadIdx.x;
  const int per = CDIM * CDIM / 4;
  int mat = idx / per, off = (idx - mat * per) * 4;
  const float* src = (mat == 0) ? W0 : (mat == 1) ? W1 : (mat == 2) ? W2 : W3;
  float4 v = *(const float4*)(src + off);
  ushort4 o;
  o.x = f2b(v.x); o.y = f2b(v.y); o.z = f2b(v.z); o.w = f2b(v.w);
  *(ushort4*)(out + (size_t)mat * (CDIM * CDIM) + off) = o;
}

// ---------------------------------------------------------------------------
// Kernel 3: rel_pos f32 (55x64) -> bf16 padded [64][64] (rows >=55 zero).
// ---------------------------------------------------------------------------
__global__ __launch_bounds__(256) void rcvt_kernel(
    const float* __restrict__ rph, const float* __restrict__ rpw,
    u16* __restrict__ Rhb, u16* __restrict__ Rwb)
{
  int idx = blockIdx.x * blockDim.x + threadIdx.x;
  if (idx >= 64 * 64) return;
  int r = idx >> 6, d = idx & 63;
  Rhb[idx] = (r < RELD) ? f2b(rph[r * DH + d]) : 0;
  Rwb[idx] = (r < RELD) ? f2b(rpw[r * DH + d]) : 0;
}

// ---------------------------------------------------------------------------
// Kernel 4a: batched MFMA GEMM for q/k/v. Tile 64x128 (wave 32x64) for TLP:
// grid (99,4,3) = 1188 blocks. Output bf16 (b,h,n,d).
// ---------------------------------------------------------------------------
__global__ __launch_bounds__(256) void mgemm3_kernel(
    const u16* __restrict__ Xq, const u16* __restrict__ Xk, const u16* __restrict__ Xv,
    const u16* __restrict__ Wb, const float* __restrict__ bq,
    const float* __restrict__ bk, const float* __restrict__ bv,
    u16* __restrict__ Yq, u16* __restrict__ Yk, u16* __restrict__ Yv)
{
  int z = blockIdx.z;
  const u16* X = (z == 0) ? Xq : (z == 1) ? Xk : Xv;
  const u16* W = Wb + (size_t)z * CDIM * CDIM;
  const float* bias = (z == 0) ? bq : (z == 1) ? bk : bv;
  u16* Y = (z == 0) ? Yq : (z == 1) ? Yk : Yv;

  int tid = threadIdx.x;
  int w = tid >> 6, lane = tid & 63, l15 = lane & 15, lg = lane >> 4;
  int m0 = blockIdx.x * 64 + (w >> 1) * 32;
  int n0 = blockIdx.y * 128 + (w & 1) * 64;

  f32x4 acc[2][4] = {};
  float bs[4];
#pragma unroll
  for (int nf = 0; nf < 4; ++nf) bs[nf] = bias[n0 + nf * 16 + l15];

  for (int k0 = 0; k0 < CDIM; k0 += 32) {
    bf16x8 a[2], b[4];
#pragma unroll
    for (int mf = 0; mf < 2; ++mf) {
      int r = m0 + mf * 16 + l15;
      if (r > ROWS - 1) r = ROWS - 1;
      a[mf] = *(const bf16x8*)(X + (size_t)r * CDIM + k0 + lg * 8);
    }
#pragma unroll
    for (int nf = 0; nf < 4; ++nf) {
      int co = n0 + nf * 16 + l15;
      b[nf] = *(const bf16x8*)(W + (size_t)co * CDIM + k0 + lg * 8);
    }
#pragma unroll
    for (int mf = 0; mf < 2; ++mf)
#pragma unroll
      for (int nf = 0; nf < 4; ++nf)
        acc[mf][nf] = __builtin_amdgcn_mfma_f32_16x16x32_bf16(a[mf], b[nf], acc[mf][nf], 0, 0, 0);
  }

#pragma unroll
  for (int mf = 0; mf < 2; ++mf) {
#pragma unroll
    for (int j = 0; j < 4; ++j) {
      int r = m0 + mf * 16 + lg * 4 + j;
      if (r >= ROWS) continue;
      int bb = r / NOUT, n = r % NOUT;
#pragma unroll
      for (int nf = 0; nf < 4; ++nf) {
        int co = n0 + nf * 16 + l15;
        float v = acc[mf][nf][j] + bs[nf];
        Y[(((size_t)bb * NH + (co >> 6)) * NOUT + n) * DH + (co & 63)] = f2b(v);
      }
    }
  }
}

// ---------------------------------------------------------------------------
// Kernel 4b: proj MFMA GEMM, 64x128 tile -> f32 row-major d_out. grid (99,4).
// ---------------------------------------------------------------------------
__global__ __launch_bounds__(256) void mgemm_proj_kernel(
    const u16* __restrict__ X, const u16* __restrict__ Wb, const float* __restrict__ bias,
    float* __restrict__ Y)
{
  int tid = threadIdx.x;
  int w = tid >> 6, lane = tid & 63, l15 = lane & 15, lg = lane >> 4;
  int m0 = blockIdx.x * 64 + (w >> 1) * 32;
  int n0 = blockIdx.y * 128 + (w & 1) * 64;

  f32x4 acc[2][4] = {};
  float bs[4];
#pragma unroll
  for (int nf = 0; nf < 4; ++nf) bs[nf] = bias[n0 + nf * 16 + l15];

  for (int k0 = 0; k0 < CDIM; k0 += 32) {
    bf16x8 a[2], b[4];
#pragma unroll
    for (int mf = 0; mf < 2; ++mf) {
      int r = m0 + mf * 16 + l15;
      if (r > ROWS - 1) r = ROWS - 1;
      a[mf] = *(const bf16x8*)(X + (size_t)r * CDIM + k0 + lg * 8);
    }
#pragma unroll
    for (int nf = 0; nf < 4; ++nf) {
      int co = n0 + nf * 16 + l15;
      b[nf] = *(const bf16x8*)(Wb + (size_t)co * CDIM + k0 + lg * 8);
    }
#pragma unroll
    for (int mf = 0; mf < 2; ++mf)
#pragma unroll
      for (int nf = 0; nf < 4; ++nf)
        acc[mf][nf] = __builtin_amdgcn_mfma_f32_16x16x32_bf16(a[mf], b[nf], acc[mf][nf], 0, 0, 0);
  }

#pragma unroll
  for (int mf = 0; mf < 2; ++mf) {
#pragma unroll
    for (int j = 0; j < 4; ++j) {
      int r = m0 + mf * 16 + lg * 4 + j;
      if (r >= ROWS) continue;
#pragma unroll
      for (int nf = 0; nf < 4; ++nf) {
        int co = n0 + nf * 16 + l15;
        Y[(size_t)r * CDIM + co] = acc[mf][nf][j] + bs[nf];
      }
    }
  }
}

// ---------------------------------------------------------------------------
// Kernel 5: flash-style MFMA attention (R11 structure, verified):
// fused rel-pos MFMA tables, double-buffered swizzled Vs (one barrier/tile),
// XCD-aware 1D grid, Q direct from global. + incremental ky/kx (R12-verified).
// LDS 39.7 KB -> 4 blocks/CU.
// ---------------------------------------------------------------------------
__global__ __launch_bounds__(256, 4) void fattn_kernel(
    const u16* __restrict__ Q, const u16* __restrict__ K, const u16* __restrict__ V,
    const u16* __restrict__ Rhb, const u16* __restrict__ Rwb,
    u16* __restrict__ O)
{
  __shared__ u16 Vs[2][64][64];     // [buf][d][k] XOR-swizzled      16384 B
  __shared__ u16 Ps[4][16][72];     // per-wave P bounce              9216 B
  __shared__ u16 relh[64][RELD];    // G_h[q][r]                      7040 B
  __shared__ u16 relw[64][RELD];    //                                7040 B

  // XCD-aware block swizzle: 832 blocks, 8 XCDs, 104 blocks/XCD.
  int bid = blockIdx.x;
  int nbid = (bid & 7) * 104 + (bid >> 3);
  int bh = nbid / NKT, qt = nbid % NKT;

  int tid = threadIdx.x;
  int w = tid >> 6, lane = tid & 63, l15 = lane & 15, lg = lane >> 4;
  size_t base = (size_t)bh * NOUT * DH;
  int q0 = qt * 64;

  int vkey_l = tid & 63;
  int vd0 = (tid >> 6) * 16;

  // ---- Q A-fragments direct from global ----
  int qrow_qi = min(q0 + w * 16 + l15, NOUT - 1);
  const u16* qp = Q + base + (size_t)qrow_qi * DH + lg * 8;
  bf16x8 qa0 = *(const bf16x8*)(qp);
  bf16x8 qa1 = *(const bf16x8*)(qp + 32);

  // ---- prologue V stage: tile 0 -> Vs[0] ----
  {
    int key = min(vkey_l, NOUT - 1);
    const u16* vp = V + base + (size_t)key * DH + vd0;
    bf16x8 v0 = *(const bf16x8*)(vp);
    bf16x8 v1 = *(const bf16x8*)(vp + 8);
#pragma unroll
    for (int i = 0; i < 8; ++i) {
      int d = vd0 + i;
      Vs[0][d][((((vkey_l >> 3) ^ (d & 7)) << 3) | (vkey_l & 7))] = (u16)v0[i];
    }
#pragma unroll
    for (int i = 0; i < 8; ++i) {
      int d = vd0 + 8 + i;
      Vs[0][d][((((vkey_l >> 3) ^ (d & 7)) << 3) | (vkey_l & 7))] = (u16)v1[i];
    }
  }

  // ---- rel-pos tables via MFMA (wave-private rows) ----
#pragma unroll
  for (int nf = 0; nf < 4; ++nf) {
    int rr = nf * 16 + l15;
    const u16* hp = Rhb + rr * 64 + lg * 8;
    bf16x8 hb0 = *(const bf16x8*)(hp);
    bf16x8 hb1 = *(const bf16x8*)(hp + 32);
    f32x4 ah = {};
    ah = __builtin_amdgcn_mfma_f32_16x16x32_bf16(qa0, hb0, ah, 0, 0, 0);
    ah = __builtin_amdgcn_mfma_f32_16x16x32_bf16(qa1, hb1, ah, 0, 0, 0);
    const u16* wp = Rwb + rr * 64 + lg * 8;
    bf16x8 wb0 = *(const bf16x8*)(wp);
    bf16x8 wb1 = *(const bf16x8*)(wp + 32);
    f32x4 aw = {};
    aw = __builtin_amdgcn_mfma_f32_16x16x32_bf16(qa0, wb0, aw, 0, 0, 0);
    aw = __builtin_amdgcn_mfma_f32_16x16x32_bf16(qa1, wb1, aw, 0, 0, 0);
    if (rr < RELD) {
#pragma unroll
      for (int j = 0; j < 4; ++j) {
        relh[w * 16 + lg * 4 + j][rr] = f2b(ah[j]);
        relw[w * 16 + lg * 4 + j][rr] = f2b(aw[j]);
      }
    }
  }

  // ---- per-j query geometry ----
  int qy_j[4], qx_j[4];
  bool qv_j[4];
#pragma unroll
  for (int j = 0; j < 4; ++j) {
    int qi = q0 + w * 16 + lg * 4 + j;
    qv_j[j] = (qi >= 1);
    int qm1 = qi - 1;
    qy_j[j] = qm1 / HO;
    qx_j[j] = qm1 % HO;
  }

  // ---- incremental key geometry per sub (verified R12) ----
  int kyr[4], kxr[4];
#pragma unroll
  for (int sub = 0; sub < 4; ++sub) {
    int km1 = sub * 16 + l15 - 1;   // -1 only for (sub=0,l15=0): unused (key<1)
    kyr[sub] = km1 / HO;
    kxr[sub] = km1 % HO;
  }

  f32x4 o0 = {}, o1 = {}, o2 = {}, o3 = {};
  float mrow[4], lrow[4];
#pragma unroll
  for (int j = 0; j < 4; ++j) { mrow[j] = -1e30f; lrow[j] = 0.f; }

  for (int t = 0; t < NKT; ++t) {
    int k0 = t * 64;
    int cur = t & 1;
    __syncthreads();   // Vs[cur] fully staged; prev tile's PV reads done

    // ---- issue next V tile's global loads FIRST ----
    bf16x8 nv0, nv1;
    bool have_next = (t + 1 < NKT);
    if (have_next) {
      int key = min(k0 + 64 + vkey_l, NOUT - 1);
      const u16* vp = V + base + (size_t)key * DH + vd0;
      nv0 = *(const bf16x8*)(vp);
      nv1 = *(const bf16x8*)(vp + 8);
    }

    // ---- K fragment loads ----
    bf16x8 kb[4][2];
#pragma unroll
    for (int sub = 0; sub < 4; ++sub) {
      int key = k0 + sub * 16 + l15;
      int keff = min(key, NOUT - 1);
      const u16* kp = K + base + (size_t)keff * DH + lg * 8;
      kb[sub][0] = *(const bf16x8*)(kp);
      kb[sub][1] = *(const bf16x8*)(kp + 32);
    }

    // ---- S = scale*Q.K^T + bias ----
    f32x4 s[4];
#pragma unroll
    for (int sub = 0; sub < 4; ++sub) {
      int key = k0 + sub * 16 + l15;
      f32x4 acc = {};
      acc = __builtin_amdgcn_mfma_f32_16x16x32_bf16(qa0, kb[sub][0], acc, 0, 0, 0);
      acc = __builtin_amdgcn_mfma_f32_16x16x32_bf16(qa1, kb[sub][1], acc, 0, 0, 0);
      bool kv = key < NOUT;
      int ky = kyr[sub], kx = kxr[sub];
#pragma unroll
      for (int j = 0; j < 4; ++j) {
        float v = acc[j] * 0.125f;
        if (key >= 1 && kv && qv_j[j]) {
          int ql = w * 16 + lg * 4 + j;
          v += b2f(relh[ql][qy_j[j] - ky + 27]) + b2f(relw[ql][qx_j[j] - kx + 27]);
        }
        if (!kv) v = -1e30f;
        s[sub][j] = v;
      }
    }

    // ---- advance key geometry (+64 keys = +2 rows +8 cols, carry) ----
#pragma unroll
    for (int sub = 0; sub < 4; ++sub) {
      kxr[sub] += 8; kyr[sub] += 2;
      if (kxr[sub] >= HO) { kxr[sub] -= HO; kyr[sub] += 1; }
    }

    // ---- write next V tile into idle buffer (no barrier needed) ----
    if (have_next) {
#pragma unroll
      for (int i = 0; i < 8; ++i) {
        int d = vd0 + i;
        Vs[cur ^ 1][d][((((vkey_l >> 3) ^ (d & 7)) << 3) | (vkey_l & 7))] = (u16)nv0[i];
      }
#pragma unroll
      for (int i = 0; i < 8; ++i) {
        int d = vd0 + 8 + i;
        Vs[cur ^ 1][d][((((vkey_l >> 3) ^ (d & 7)) << 3) | (vkey_l & 7))] = (u16)nv1[i];
      }
    }

    // ---- online softmax ----
    float alpha[4];
#pragma unroll
    for (int j = 0; j < 4; ++j) {
      float lm = fmaxf(fmaxf(s[0][j], s[1][j]), fmaxf(s[2][j], s[3][j]));
      lm = fmaxf(lm, __shfl_xor(lm, 1));
      lm = fmaxf(lm, __shfl_xor(lm, 2));
      lm = fmaxf(lm, __shfl_xor(lm, 4));
      lm = fmaxf(lm, __shfl_xor(lm, 8));
      float mnew = fmaxf(mrow[j], lm);
      alpha[j] = __expf(mrow[j] - mnew);
      mrow[j] = mnew;
      float ps = 0.f;
#pragma unroll
      for (int sub = 0; sub < 4; ++sub) {
        float pv = __expf(s[sub][j] - mnew);
        s[sub][j] = pv;
        ps += pv;
      }
      ps += __shfl_xor(ps, 1);
      ps += __shfl_xor(ps, 2);
      ps += __shfl_xor(ps, 4);
      ps += __shfl_xor(ps, 8);
      lrow[j] = lrow[j] * alpha[j] + ps;
    }

    // ---- rescale O, bounce P (wave-private) ----
#pragma unroll
    for (int j = 0; j < 4; ++j) {
      o0[j] *= alpha[j]; o1[j] *= alpha[j]; o2[j] *= alpha[j]; o3[j] *= alpha[j];
      Ps[w][lg * 4 + j][ 0 + l15] = f2b(s[0][j]);
      Ps[w][lg * 4 + j][16 + l15] = f2b(s[1][j]);
      Ps[w][lg * 4 + j][32 + l15] = f2b(s[2][j]);
      Ps[w][lg * 4 + j][48 + l15] = f2b(s[3][j]);
    }

    // ---- O += P.V from Vs[cur] ----
    bf16x8 pa0 = *(const bf16x8*)&Ps[w][l15][lg * 8];
    bf16x8 pa1 = *(const bf16x8*)&Ps[w][l15][32 + lg * 8];
    {
      int r = 0 + l15;
      bf16x8 vb0 = *(const bf16x8*)&Vs[cur][r][((lg ^ (r & 7)) << 3)];
      bf16x8 vb1 = *(const bf16x8*)&Vs[cur][r][(((4 + lg) ^ (r & 7)) << 3)];
      o0 = __builtin_amdgcn_mfma_f32_16x16x32_bf16(pa0, vb0, o0, 0, 0, 0);
      o0 = __builtin_amdgcn_mfma_f32_16x16x32_bf16(pa1, vb1, o0, 0, 0, 0);
    }
    {
      int r = 16 + l15;
      bf16x8 vb0 = *(const bf16x8*)&Vs[cur][r][((lg ^ (r & 7)) << 3)];
      bf16x8 vb1 = *(const bf16x8*)&Vs[cur][r][(((4 + lg) ^ (r & 7)) << 3)];
      o1 = __builtin_amdgcn_mfma_f32_16x16x32_bf16(pa0, vb0, o1, 0, 0, 0);
      o1 = __builtin_amdgcn_mfma_f32_16x16x32_bf16(pa1, vb1, o1, 0, 0, 0);
    }
    {
      int r = 32 + l15;
      bf16x8 vb0 = *(const bf16x8*)&Vs[cur][r][((lg ^ (r & 7)) << 3)];
      bf16x8 vb1 = *(const bf16x8*)&Vs[cur][r][(((4 + lg) ^ (r & 7)) << 3)];
      o2 = __builtin_amdgcn_mfma_f32_16x16x32_bf16(pa0, vb0, o2, 0, 0, 0);
      o2 = __builtin_amdgcn_mfma_f32_16x16x32_bf16(pa1, vb1, o2, 0, 0, 0);
    }
    {
      int r = 48 + l15;
      bf16x8 vb0 = *(const bf16x8*)&Vs[cur][r][((lg ^ (r & 7)) << 3)];
      bf16x8 vb1 = *(const bf16x8*)&Vs[cur][r][(((4 + lg) ^ (r & 7)) << 3)];
      o3 = __builtin_amdgcn_mfma_f32_16x16x32_bf16(pa0, vb0, o3, 0, 0, 0);
      o3 = __builtin_amdgcn_mfma_f32_16x16x32_bf16(pa1, vb1, o3, 0, 0, 0);
    }
  }

  // ---- epilogue: normalize, residual (Q re-read from global), store ----
  int b = bh >> 3, h = bh & 7;
#pragma unroll
  for (int j = 0; j < 4; ++j) {
    int ql = w * 16 + lg * 4 + j;
    int qi = q0 + ql;
    if (qi >= NOUT) continue;
    float inv = 1.f / lrow[j];
    float v0 = o0[j] * inv, v1 = o1[j] * inv, v2 = o2[j] * inv, v3 = o3[j] * inv;
    if (qi > 0) {
      const u16* qp2 = Q + base + (size_t)qi * DH;
      v0 += b2f(qp2[ 0 + l15]);
      v1 += b2f(qp2[16 + l15]);
      v2 += b2f(qp2[32 + l15]);
      v3 += b2f(qp2[48 + l15]);
    }
    size_t ob = ((size_t)b * NOUT + qi) * CDIM + h * DH;
    O[ob +  0 + l15] = f2b(v0);
    O[ob + 16 + l15] = f2b(v1);
    O[ob + 32 + l15] = f2b(v2);
    O[ob + 48 + l15] = f2b(v3);
  }
}

// ---------------------------------------------------------------------------
// ws layout (u16): s0..s4 (5 x PSZ), Wb (4 x WSZ), Rhb/Rwb (2 x 4096). ~34 MB.
// Schedule: pool: Pq->s0, Pk->s1, Pv->s2
//           mgemm3: s0->qbuf(Q), s1->s3(K), s2->s4(V)   [disjoint in/out]
//           fattn:  (qbuf,s3,s4) -> s0
//           proj:   s0 -> d_out (f32, overwrites qbuf; Q dead)
// ---------------------------------------------------------------------------
extern "C" void kernel_launch(void* const* d_in, const int* in_sizes, int n_in,
                              void* d_out, int out_size, void* d_ws, size_t ws_size,
                              hipStream_t stream) {
  const float* x     = (const float*)d_in[0];
  const float* xr    = (const float*)d_in[1];
  const float* wq    = (const float*)d_in[2];
  const float* bq    = (const float*)d_in[3];
  const float* wk    = (const float*)d_in[4];
  const float* bk    = (const float*)d_in[5];
  const float* wv    = (const float*)d_in[6];
  const float* bv    = (const float*)d_in[7];
  const float* wpj   = (const float*)d_in[8];
  const float* bpj   = (const float*)d_in[9];
  const float* cwq   = (const float*)d_in[10];
  const float* cwk   = (const float*)d_in[11];
  const float* cwv   = (const float*)d_in[12];
  const float* gq    = (const float*)d_in[13];
  const float* lbq   = (const float*)d_in[14];
  const float* gk    = (const float*)d_in[15];
  const float* lbk   = (const float*)d_in[16];
  const float* gv    = (const float*)d_in[17];
  const float* lbv   = (const float*)d_in[18];
  const float* rph   = (const float*)d_in[19];
  const float* rpw   = (const float*)d_in[20];
  (void)in_sizes; (void)n_in; (void)out_size; (void)ws_size;

  u16* ws = (u16*)d_ws;
  const size_t PSZ = (size_t)ROWS * CDIM;
  const size_t WSZ = (size_t)CDIM * CDIM;
  u16* s0 = ws + 0 * PSZ;
  u16* s1 = ws + 1 * PSZ;
  u16* s2 = ws + 2 * PSZ;
  u16* s3 = ws + 3 * PSZ;
  u16* s4 = ws + 4 * PSZ;
  u16* Wb  = ws + 5 * PSZ;
  u16* Rhb = Wb + 4 * WSZ;
  u16* Rwb = Rhb + 64 * 64;
  u16* qbuf = (u16*)d_out;              // bf16 scratch inside f32 output buffer

  // 1) pool + layernorm: Pq->s0, Pk->s1, Pv->s2
  pool_ln_kernel<<<dim3((NOUT + 3) / 4, 64, 2), 256, 0, stream>>>(
      x, xr, cwq, cwk, cwv, gq, lbq, gk, lbk, gv, lbv, s0, s1, s2);

  // 2) weights + rel_pos -> bf16
  wcvt_kernel<<<(4 * CDIM * CDIM / 4 + 255) / 256, 256, 0, stream>>>(wq, wk, wv, wpj, Wb);
  rcvt_kernel<<<16, 256, 0, stream>>>(rph, rpw, Rhb, Rwb);

  // 3) q/k/v projections: q: s0->qbuf, k: s1->s3, v: s2->s4
  dim3 g3((ROWS + 63) / 64, CDIM / 128, 3);
  mgemm3_kernel<<<g3, 256, 0, stream>>>(s0, s1, s2, Wb, bq, bk, bv, qbuf, s3, s4);

  // 4) attention -> s0
  fattn_kernel<<<NKT * 64, 256, 0, stream>>>(qbuf, s3, s4, Rhb, Rwb, s0);

  // 5) output projection -> f32 d_out
  dim3 gp((ROWS + 63) / 64, CDIM / 128);
  mgemm_proj_kernel<<<gp, 256, 0, stream>>>(s0, Wb + 3 * WSZ, bpj, (float*)d_out);
}

// Round 14
// 198.224 us; speedup vs baseline: 1.6285x; 1.1012x over previous
//
#include <hip/hip_runtime.h>

// Problem constants (B=8, T=1, H=56, C=512, nh=8, d=64)
// Inputs: float32. Output: float32. ws intermediates: bf16.
#define NH    8
#define DH    64
#define NTOK  3137      // 56*56+1
#define NOUT  785       // 28*28+1
#define CDIM  512
#define ROWS  6280      // 8*785
#define HO    28
#define HIN   56
#define NKT   13        // ceil(785/64) key tiles
#define RELD  55        // 2*(56//2)-1

typedef unsigned short u16;
typedef __attribute__((ext_vector_type(8))) short bf16x8;   // 8 bf16 = 4 VGPRs
typedef __attribute__((ext_vector_type(4))) float f32x4;    // MFMA C/D

__device__ __forceinline__ float b2f(u16 u) { return __uint_as_float(((unsigned)u) << 16); }
__device__ __forceinline__ u16 f2b(float f) {
  unsigned u = __float_as_uint(f);
  return (u16)((u + 0x7FFFu + ((u >> 16) & 1u)) >> 16);
}

// ---------------------------------------------------------------------------
// Kernel 1: depthwise 3x3 stride-2 pool + LayerNorm(64), float4-vectorized.
// Thread = (b, token, 4-channel group): 128 threads span 512 channels; block
// of 256 covers 2 tokens. LN over the 16-lane head group (shfl_xor 1,2,4,8).
// z=0: q from x. z=1: k AND v from x_ref (shared conv reads).
// ---------------------------------------------------------------------------
__global__ __launch_bounds__(256) void pool_ln_kernel(
    const float* __restrict__ x, const float* __restrict__ xr,
    const float* __restrict__ cwq, const float* __restrict__ cwk, const float* __restrict__ cwv,
    const float* __restrict__ gq, const float* __restrict__ bq,
    const float* __restrict__ gk, const float* __restrict__ bk,
    const float* __restrict__ gv, const float* __restrict__ bv,
    u16* __restrict__ Pq, u16* __restrict__ Pk, u16* __restrict__ Pv)
{
  int tid   = threadIdx.x;
  int n     = blockIdx.x * 2 + (tid >> 7);           // token (wave-uniform half)
  int b     = blockIdx.y;
  int which = blockIdx.z;                            // 0=q(x), 1=k+v(x_ref)
  if (n >= NOUT) return;
  int c4 = tid & 127;                                // float4 index in 512 ch
  int c  = c4 * 4;
  int d0 = c & 63;                                   // channel-in-head offset

  const float* src  = which ? xr : x;
  const float* srcb = src + (size_t)b * NTOK * CDIM + c;
  size_t obase = (size_t)(b * NOUT + n) * CDIM + c;

  float4 vq = make_float4(0.f, 0.f, 0.f, 0.f);
  float4 vk = make_float4(0.f, 0.f, 0.f, 0.f);
  const float* cw0 = which ? cwk : cwq;

  if (n == 0) {
    float4 t = *(const float4*)(srcb);               // cls token (token 0)
    vq = t; vk = t;
  } else {
    int oy = (n - 1) / HO, ox = (n - 1) % HO;
#pragma unroll
    for (int ky = 0; ky < 3; ++ky) {
      int iy = oy * 2 - 1 + ky;
      if (iy < 0 || iy >= HIN) continue;
#pragma unroll
      for (int kx = 0; kx < 3; ++kx) {
        int ix = ox * 2 - 1 + kx;
        if (ix < 0 || ix >= HIN) continue;
        int tok = 1 + iy * HIN + ix;
        float4 t  = *(const float4*)(srcb + (size_t)tok * CDIM);
        float4 w0 = *(const float4*)(cw0 + (ky * 3 + kx) * DH + d0);
        vq.x += t.x * w0.x; vq.y += t.y * w0.y; vq.z += t.z * w0.z; vq.w += t.w * w0.w;
        if (which) {
          float4 w1 = *(const float4*)(cwv + (ky * 3 + kx) * DH + d0);
          vk.x += t.x * w1.x; vk.y += t.y * w1.y; vk.z += t.z * w1.z; vk.w += t.w * w1.w;
        }
      }
    }
  }

  // LN over the 16-lane head group; 4 channels/thread
  {
    float s  = vq.x + vq.y + vq.z + vq.w;
    float sq = vq.x * vq.x + vq.y * vq.y + vq.z * vq.z + vq.w * vq.w;
#pragma unroll
    for (int off = 1; off < 16; off <<= 1) {
      s  += __shfl_xor(s, off, 64);
      sq += __shfl_xor(sq, off, 64);
    }
    float mu  = s * (1.f / 64.f);
    float var = sq * (1.f / 64.f) - mu * mu;
    float inv = rsqrtf(var + 1e-5f);
    const float* g  = which ? gk : gq;
    const float* be = which ? bk : bq;
    float4 gg = *(const float4*)(g + d0);
    float4 bb = *(const float4*)(be + d0);
    ushort4 o;
    o.x = f2b((vq.x - mu) * inv * gg.x + bb.x);
    o.y = f2b((vq.y - mu) * inv * gg.y + bb.y);
    o.z = f2b((vq.z - mu) * inv * gg.z + bb.z);
    o.w = f2b((vq.w - mu) * inv * gg.w + bb.w);
    *(ushort4*)(((which ? Pk : Pq)) + obase) = o;
  }
  if (which) {
    float s  = vk.x + vk.y + vk.z + vk.w;
    float sq = vk.x * vk.x + vk.y * vk.y + vk.z * vk.z + vk.w * vk.w;
#pragma unroll
    for (int off = 1; off < 16; off <<= 1) {
      s  += __shfl_xor(s, off, 64);
      sq += __shfl_xor(sq, off, 64);
    }
    float mu  = s * (1.f / 64.f);
    float var = sq * (1.f / 64.f) - mu * mu;
    float inv = rsqrtf(var + 1e-5f);
    float4 gg = *(const float4*)(gv + d0);
    float4 bb = *(const float4*)(bv + d0);
    ushort4 o;
    o.x = f2b((vk.x - mu) * inv * gg.x + bb.x);
    o.y = f2b((vk.y - mu) * inv * gg.y + bb.y);
    o.z = f2b((vk.z - mu) * inv * gg.z + bb.z);
    o.w = f2b((vk.w - mu) * inv * gg.w + bb.w);
    *(ushort4*)(Pv + obase) = o;
  }
}

// ---------------------------------------------------------------------------
// Kernel 2: convert the four 512x512 f32 weight matrices to bf16 (packed).
// ---------------------------------------------------------------------------
__global__ __launch_bounds__(256) void wcvt_kernel(
    const float* __restrict__ W0, const float* __restrict__ W1,
    const float* __restrict__ W2, const float* __restrict__ W3,
    u16* __restrict__ out)
{
  int idx = blockIdx.x * blockDim.x + threadIdx.x;
  const int per = CDIM * CDIM / 4;
  int mat = idx / per, off = (idx - mat * per) * 4;
  const float* src = (mat == 0) ? W0 : (mat == 1) ? W1 : (mat == 2) ? W2 : W3;
  float4 v = *(const float4*)(src + off);
  ushort4 o;
  o.x = f2b(v.x); o.y = f2b(v.y); o.z = f2b(v.z); o.w = f2b(v.w);
  *(ushort4*)(out + (size_t)mat * (CDIM * CDIM) + off) = o;
}

// ---------------------------------------------------------------------------
// Kernel 3: rel_pos f32 (55x64) -> bf16 padded [64][64] (rows >=55 zero).
// ---------------------------------------------------------------------------
__global__ __launch_bounds__(256) void rcvt_kernel(
    const float* __restrict__ rph, const float* __restrict__ rpw,
    u16* __restrict__ Rhb, u16* __restrict__ Rwb)
{
  int idx = blockIdx.x * blockDim.x + threadIdx.x;
  if (idx >= 64 * 64) return;
  int r = idx >> 6, d = idx & 63;
  Rhb[idx] = (r < RELD) ? f2b(rph[r * DH + d]) : 0;
  Rwb[idx] = (r < RELD) ? f2b(rpw[r * DH + d]) : 0;
}

// ---------------------------------------------------------------------------
// Kernel 4a: batched MFMA GEMM for q/k/v. Tile 64x128 (wave 32x64) for TLP:
// grid (99,4,3) = 1188 blocks. Output bf16 (b,h,n,d).
// ---------------------------------------------------------------------------
__global__ __launch_bounds__(256) void mgemm3_kernel(
    const u16* __restrict__ Xq, const u16* __restrict__ Xk, const u16* __restrict__ Xv,
    const u16* __restrict__ Wb, const float* __restrict__ bq,
    const float* __restrict__ bk, const float* __restrict__ bv,
    u16* __restrict__ Yq, u16* __restrict__ Yk, u16* __restrict__ Yv)
{
  int z = blockIdx.z;
  const u16* X = (z == 0) ? Xq : (z == 1) ? Xk : Xv;
  const u16* W = Wb + (size_t)z * CDIM * CDIM;
  const float* bias = (z == 0) ? bq : (z == 1) ? bk : bv;
  u16* Y = (z == 0) ? Yq : (z == 1) ? Yk : Yv;

  int tid = threadIdx.x;
  int w = tid >> 6, lane = tid & 63, l15 = lane & 15, lg = lane >> 4;
  int m0 = blockIdx.x * 64 + (w >> 1) * 32;
  int n0 = blockIdx.y * 128 + (w & 1) * 64;

  f32x4 acc[2][4] = {};
  float bs[4];
#pragma unroll
  for (int nf = 0; nf < 4; ++nf) bs[nf] = bias[n0 + nf * 16 + l15];

  for (int k0 = 0; k0 < CDIM; k0 += 32) {
    bf16x8 a[2], b[4];
#pragma unroll
    for (int mf = 0; mf < 2; ++mf) {
      int r = m0 + mf * 16 + l15;
      if (r > ROWS - 1) r = ROWS - 1;
      a[mf] = *(const bf16x8*)(X + (size_t)r * CDIM + k0 + lg * 8);
    }
#pragma unroll
    for (int nf = 0; nf < 4; ++nf) {
      int co = n0 + nf * 16 + l15;
      b[nf] = *(const bf16x8*)(W + (size_t)co * CDIM + k0 + lg * 8);
    }
#pragma unroll
    for (int mf = 0; mf < 2; ++mf)
#pragma unroll
      for (int nf = 0; nf < 4; ++nf)
        acc[mf][nf] = __builtin_amdgcn_mfma_f32_16x16x32_bf16(a[mf], b[nf], acc[mf][nf], 0, 0, 0);
  }

#pragma unroll
  for (int mf = 0; mf < 2; ++mf) {
#pragma unroll
    for (int j = 0; j < 4; ++j) {
      int r = m0 + mf * 16 + lg * 4 + j;
      if (r >= ROWS) continue;
      int bb = r / NOUT, n = r % NOUT;
#pragma unroll
      for (int nf = 0; nf < 4; ++nf) {
        int co = n0 + nf * 16 + l15;
        float v = acc[mf][nf][j] + bs[nf];
        Y[(((size_t)bb * NH + (co >> 6)) * NOUT + n) * DH + (co & 63)] = f2b(v);
      }
    }
  }
}

// ---------------------------------------------------------------------------
// Kernel 4b: proj MFMA GEMM, 64x128 tile -> f32 row-major d_out. grid (99,4).
// ---------------------------------------------------------------------------
__global__ __launch_bounds__(256) void mgemm_proj_kernel(
    const u16* __restrict__ X, const u16* __restrict__ Wb, const float* __restrict__ bias,
    float* __restrict__ Y)
{
  int tid = threadIdx.x;
  int w = tid >> 6, lane = tid & 63, l15 = lane & 15, lg = lane >> 4;
  int m0 = blockIdx.x * 64 + (w >> 1) * 32;
  int n0 = blockIdx.y * 128 + (w & 1) * 64;

  f32x4 acc[2][4] = {};
  float bs[4];
#pragma unroll
  for (int nf = 0; nf < 4; ++nf) bs[nf] = bias[n0 + nf * 16 + l15];

  for (int k0 = 0; k0 < CDIM; k0 += 32) {
    bf16x8 a[2], b[4];
#pragma unroll
    for (int mf = 0; mf < 2; ++mf) {
      int r = m0 + mf * 16 + l15;
      if (r > ROWS - 1) r = ROWS - 1;
      a[mf] = *(const bf16x8*)(X + (size_t)r * CDIM + k0 + lg * 8);
    }
#pragma unroll
    for (int nf = 0; nf < 4; ++nf) {
      int co = n0 + nf * 16 + l15;
      b[nf] = *(const bf16x8*)(Wb + (size_t)co * CDIM + k0 + lg * 8);
    }
#pragma unroll
    for (int mf = 0; mf < 2; ++mf)
#pragma unroll
      for (int nf = 0; nf < 4; ++nf)
        acc[mf][nf] = __builtin_amdgcn_mfma_f32_16x16x32_bf16(a[mf], b[nf], acc[mf][nf], 0, 0, 0);
  }

#pragma unroll
  for (int mf = 0; mf < 2; ++mf) {
#pragma unroll
    for (int j = 0; j < 4; ++j) {
      int r = m0 + mf * 16 + lg * 4 + j;
      if (r >= ROWS) continue;
#pragma unroll
      for (int nf = 0; nf < 4; ++nf) {
        int co = n0 + nf * 16 + l15;
        Y[(size_t)r * CDIM + co] = acc[mf][nf][j] + bs[nf];
      }
    }
  }
}

// ---------------------------------------------------------------------------
// Kernel 5: flash-style MFMA attention (R11 structure + incremental ky/kx).
// LDS 39.7 KB -> 4 blocks/CU. XCD-aware 1D grid.
// ---------------------------------------------------------------------------
__global__ __launch_bounds__(256, 4) void fattn_kernel(
    const u16* __restrict__ Q, const u16* __restrict__ K, const u16* __restrict__ V,
    const u16* __restrict__ Rhb, const u16* __restrict__ Rwb,
    u16* __restrict__ O)
{
  __shared__ u16 Vs[2][64][64];     // [buf][d][k] XOR-swizzled      16384 B
  __shared__ u16 Ps[4][16][72];     // per-wave P bounce              9216 B
  __shared__ u16 relh[64][RELD];    // G_h[q][r]                      7040 B
  __shared__ u16 relw[64][RELD];    //                                7040 B

  int bid = blockIdx.x;
  int nbid = (bid & 7) * 104 + (bid >> 3);
  int bh = nbid / NKT, qt = nbid % NKT;

  int tid = threadIdx.x;
  int w = tid >> 6, lane = tid & 63, l15 = lane & 15, lg = lane >> 4;
  size_t base = (size_t)bh * NOUT * DH;
  int q0 = qt * 64;

  int vkey_l = tid & 63;
  int vd0 = (tid >> 6) * 16;

  // ---- Q A-fragments direct from global ----
  int qrow_qi = min(q0 + w * 16 + l15, NOUT - 1);
  const u16* qp = Q + base + (size_t)qrow_qi * DH + lg * 8;
  bf16x8 qa0 = *(const bf16x8*)(qp);
  bf16x8 qa1 = *(const bf16x8*)(qp + 32);

  // ---- prologue V stage: tile 0 -> Vs[0] ----
  {
    int key = min(vkey_l, NOUT - 1);
    const u16* vp = V + base + (size_t)key * DH + vd0;
    bf16x8 v0 = *(const bf16x8*)(vp);
    bf16x8 v1 = *(const bf16x8*)(vp + 8);
#pragma unroll
    for (int i = 0; i < 8; ++i) {
      int d = vd0 + i;
      Vs[0][d][((((vkey_l >> 3) ^ (d & 7)) << 3) | (vkey_l & 7))] = (u16)v0[i];
    }
#pragma unroll
    for (int i = 0; i < 8; ++i) {
      int d = vd0 + 8 + i;
      Vs[0][d][((((vkey_l >> 3) ^ (d & 7)) << 3) | (vkey_l & 7))] = (u16)v1[i];
    }
  }

  // ---- rel-pos tables via MFMA (wave-private rows) ----
#pragma unroll
  for (int nf = 0; nf < 4; ++nf) {
    int rr = nf * 16 + l15;
    const u16* hp = Rhb + rr * 64 + lg * 8;
    bf16x8 hb0 = *(const bf16x8*)(hp);
    bf16x8 hb1 = *(const bf16x8*)(hp + 32);
    f32x4 ah = {};
    ah = __builtin_amdgcn_mfma_f32_16x16x32_bf16(qa0, hb0, ah, 0, 0, 0);
    ah = __builtin_amdgcn_mfma_f32_16x16x32_bf16(qa1, hb1, ah, 0, 0, 0);
    const u16* wp = Rwb + rr * 64 + lg * 8;
    bf16x8 wb0 = *(const bf16x8*)(wp);
    bf16x8 wb1 = *(const bf16x8*)(wp + 32);
    f32x4 aw = {};
    aw = __builtin_amdgcn_mfma_f32_16x16x32_bf16(qa0, wb0, aw, 0, 0, 0);
    aw = __builtin_amdgcn_mfma_f32_16x16x32_bf16(qa1, wb1, aw, 0, 0, 0);
    if (rr < RELD) {
#pragma unroll
      for (int j = 0; j < 4; ++j) {
        relh[w * 16 + lg * 4 + j][rr] = f2b(ah[j]);
        relw[w * 16 + lg * 4 + j][rr] = f2b(aw[j]);
      }
    }
  }

  // ---- per-j query geometry ----
  int qy_j[4], qx_j[4];
  bool qv_j[4];
#pragma unroll
  for (int j = 0; j < 4; ++j) {
    int qi = q0 + w * 16 + lg * 4 + j;
    qv_j[j] = (qi >= 1);
    int qm1 = qi - 1;
    qy_j[j] = qm1 / HO;
    qx_j[j] = qm1 % HO;
  }

  // ---- incremental key geometry per sub ----
  int kyr[4], kxr[4];
#pragma unroll
  for (int sub = 0; sub < 4; ++sub) {
    int km1 = sub * 16 + l15 - 1;   // -1 only for (sub=0,l15=0): unused (key<1)
    kyr[sub] = km1 / HO;
    kxr[sub] = km1 % HO;
  }

  f32x4 o0 = {}, o1 = {}, o2 = {}, o3 = {};
  float mrow[4], lrow[4];
#pragma unroll
  for (int j = 0; j < 4; ++j) { mrow[j] = -1e30f; lrow[j] = 0.f; }

  for (int t = 0; t < NKT; ++t) {
    int k0 = t * 64;
    int cur = t & 1;
    __syncthreads();   // Vs[cur] fully staged; prev tile's PV reads done

    // ---- issue next V tile's global loads FIRST ----
    bf16x8 nv0, nv1;
    bool have_next = (t + 1 < NKT);
    if (have_next) {
      int key = min(k0 + 64 + vkey_l, NOUT - 1);
      const u16* vp = V + base + (size_t)key * DH + vd0;
      nv0 = *(const bf16x8*)(vp);
      nv1 = *(const bf16x8*)(vp + 8);
    }

    // ---- K fragment loads ----
    bf16x8 kb[4][2];
#pragma unroll
    for (int sub = 0; sub < 4; ++sub) {
      int key = k0 + sub * 16 + l15;
      int keff = min(key, NOUT - 1);
      const u16* kp = K + base + (size_t)keff * DH + lg * 8;
      kb[sub][0] = *(const bf16x8*)(kp);
      kb[sub][1] = *(const bf16x8*)(kp + 32);
    }

    // ---- S = scale*Q.K^T + bias ----
    f32x4 s[4];
#pragma unroll
    for (int sub = 0; sub < 4; ++sub) {
      int key = k0 + sub * 16 + l15;
      f32x4 acc = {};
      acc = __builtin_amdgcn_mfma_f32_16x16x32_bf16(qa0, kb[sub][0], acc, 0, 0, 0);
      acc = __builtin_amdgcn_mfma_f32_16x16x32_bf16(qa1, kb[sub][1], acc, 0, 0, 0);
      bool kv = key < NOUT;
      int ky = kyr[sub], kx = kxr[sub];
#pragma unroll
      for (int j = 0; j < 4; ++j) {
        float v = acc[j] * 0.125f;
        if (key >= 1 && kv && qv_j[j]) {
          int ql = w * 16 + lg * 4 + j;
          v += b2f(relh[ql][qy_j[j] - ky + 27]) + b2f(relw[ql][qx_j[j] - kx + 27]);
        }
        if (!kv) v = -1e30f;
        s[sub][j] = v;
      }
    }

    // ---- advance key geometry (+64 keys = +2 rows +8 cols, carry) ----
#pragma unroll
    for (int sub = 0; sub < 4; ++sub) {
      kxr[sub] += 8; kyr[sub] += 2;
      if (kxr[sub] >= HO) { kxr[sub] -= HO; kyr[sub] += 1; }
    }

    // ---- write next V tile into idle buffer (no barrier needed) ----
    if (have_next) {
#pragma unroll
      for (int i = 0; i < 8; ++i) {
        int d = vd0 + i;
        Vs[cur ^ 1][d][((((vkey_l >> 3) ^ (d & 7)) << 3) | (vkey_l & 7))] = (u16)nv0[i];
      }
#pragma unroll
      for (int i = 0; i < 8; ++i) {
        int d = vd0 + 8 + i;
        Vs[cur ^ 1][d][((((vkey_l >> 3) ^ (d & 7)) << 3) | (vkey_l & 7))] = (u16)nv1[i];
      }
    }

    // ---- online softmax ----
    float alpha[4];
#pragma unroll
    for (int j = 0; j < 4; ++j) {
      float lm = fmaxf(fmaxf(s[0][j], s[1][j]), fmaxf(s[2][j], s[3][j]));
      lm = fmaxf(lm, __shfl_xor(lm, 1));
      lm = fmaxf(lm, __shfl_xor(lm, 2));
      lm = fmaxf(lm, __shfl_xor(lm, 4));
      lm = fmaxf(lm, __shfl_xor(lm, 8));
      float mnew = fmaxf(mrow[j], lm);
      alpha[j] = __expf(mrow[j] - mnew);
      mrow[j] = mnew;
      float ps = 0.f;
#pragma unroll
      for (int sub = 0; sub < 4; ++sub) {
        float pv = __expf(s[sub][j] - mnew);
        s[sub][j] = pv;
        ps += pv;
      }
      ps += __shfl_xor(ps, 1);
      ps += __shfl_xor(ps, 2);
      ps += __shfl_xor(ps, 4);
      ps += __shfl_xor(ps, 8);
      lrow[j] = lrow[j] * alpha[j] + ps;
    }

    // ---- rescale O, bounce P (wave-private) ----
#pragma unroll
    for (int j = 0; j < 4; ++j) {
      o0[j] *= alpha[j]; o1[j] *= alpha[j]; o2[j] *= alpha[j]; o3[j] *= alpha[j];
      Ps[w][lg * 4 + j][ 0 + l15] = f2b(s[0][j]);
      Ps[w][lg * 4 + j][16 + l15] = f2b(s[1][j]);
      Ps[w][lg * 4 + j][32 + l15] = f2b(s[2][j]);
      Ps[w][lg * 4 + j][48 + l15] = f2b(s[3][j]);
    }

    // ---- O += P.V from Vs[cur] ----
    bf16x8 pa0 = *(const bf16x8*)&Ps[w][l15][lg * 8];
    bf16x8 pa1 = *(const bf16x8*)&Ps[w][l15][32 + lg * 8];
    {
      int r = 0 + l15;
      bf16x8 vb0 = *(const bf16x8*)&Vs[cur][r][((lg ^ (r & 7)) << 3)];
      bf16x8 vb1 = *(const bf16x8*)&Vs[cur][r][(((4 + lg) ^ (r & 7)) << 3)];
      o0 = __builtin_amdgcn_mfma_f32_16x16x32_bf16(pa0, vb0, o0, 0, 0, 0);
      o0 = __builtin_amdgcn_mfma_f32_16x16x32_bf16(pa1, vb1, o0, 0, 0, 0);
    }
    {
      int r = 16 + l15;
      bf16x8 vb0 = *(const bf16x8*)&Vs[cur][r][((lg ^ (r & 7)) << 3)];
      bf16x8 vb1 = *(const bf16x8*)&Vs[cur][r][(((4 + lg) ^ (r & 7)) << 3)];
      o1 = __builtin_amdgcn_mfma_f32_16x16x32_bf16(pa0, vb0, o1, 0, 0, 0);
      o1 = __builtin_amdgcn_mfma_f32_16x16x32_bf16(pa1, vb1, o1, 0, 0, 0);
    }
    {
      int r = 32 + l15;
      bf16x8 vb0 = *(const bf16x8*)&Vs[cur][r][((lg ^ (r & 7)) << 3)];
      bf16x8 vb1 = *(const bf16x8*)&Vs[cur][r][(((4 + lg) ^ (r & 7)) << 3)];
      o2 = __builtin_amdgcn_mfma_f32_16x16x32_bf16(pa0, vb0, o2, 0, 0, 0);
      o2 = __builtin_amdgcn_mfma_f32_16x16x32_bf16(pa1, vb1, o2, 0, 0, 0);
    }
    {
      int r = 48 + l15;
      bf16x8 vb0 = *(const bf16x8*)&Vs[cur][r][((lg ^ (r & 7)) << 3)];
      bf16x8 vb1 = *(const bf16x8*)&Vs[cur][r][(((4 + lg) ^ (r & 7)) << 3)];
      o3 = __builtin_amdgcn_mfma_f32_16x16x32_bf16(pa0, vb0, o3, 0, 0, 0);
      o3 = __builtin_amdgcn_mfma_f32_16x16x32_bf16(pa1, vb1, o3, 0, 0, 0);
    }
  }

  // ---- epilogue: normalize, residual (Q re-read from global), store ----
  int b = bh >> 3, h = bh & 7;
#pragma unroll
  for (int j = 0; j < 4; ++j) {
    int ql = w * 16 + lg * 4 + j;
    int qi = q0 + ql;
    if (qi >= NOUT) continue;
    float inv = 1.f / lrow[j];
    float v0 = o0[j] * inv, v1 = o1[j] * inv, v2 = o2[j] * inv, v3 = o3[j] * inv;
    if (qi > 0) {
      const u16* qp2 = Q + base + (size_t)qi * DH;
      v0 += b2f(qp2[ 0 + l15]);
      v1 += b2f(qp2[16 + l15]);
      v2 += b2f(qp2[32 + l15]);
      v3 += b2f(qp2[48 + l15]);
    }
    size_t ob = ((size_t)b * NOUT + qi) * CDIM + h * DH;
    O[ob +  0 + l15] = f2b(v0);
    O[ob + 16 + l15] = f2b(v1);
    O[ob + 32 + l15] = f2b(v2);
    O[ob + 48 + l15] = f2b(v3);
  }
}

// ---------------------------------------------------------------------------
// ws layout (u16): s0..s4 (5 x PSZ), Wb (4 x WSZ), Rhb/Rwb (2 x 4096). ~34 MB.
// Schedule: pool: Pq->s0, Pk->s1, Pv->s2
//           mgemm3: s0->qbuf(Q), s1->s3(K), s2->s4(V)   [disjoint in/out]
//           fattn:  (qbuf,s3,s4) -> s0
//           proj:   s0 -> d_out (f32, overwrites qbuf; Q dead)
// ---------------------------------------------------------------------------
extern "C" void kernel_launch(void* const* d_in, const int* in_sizes, int n_in,
                              void* d_out, int out_size, void* d_ws, size_t ws_size,
                              hipStream_t stream) {
  const float* x     = (const float*)d_in[0];
  const float* xr    = (const float*)d_in[1];
  const float* wq    = (const float*)d_in[2];
  const float* bq    = (const float*)d_in[3];
  const float* wk    = (const float*)d_in[4];
  const float* bk    = (const float*)d_in[5];
  const float* wv    = (const float*)d_in[6];
  const float* bv    = (const float*)d_in[7];
  const float* wpj   = (const float*)d_in[8];
  const float* bpj   = (const float*)d_in[9];
  const float* cwq   = (const float*)d_in[10];
  const float* cwk   = (const float*)d_in[11];
  const float* cwv   = (const float*)d_in[12];
  const float* gq    = (const float*)d_in[13];
  const float* lbq   = (const float*)d_in[14];
  const float* gk    = (const float*)d_in[15];
  const float* lbk   = (const float*)d_in[16];
  const float* gv    = (const float*)d_in[17];
  const float* lbv   = (const float*)d_in[18];
  const float* rph   = (const float*)d_in[19];
  const float* rpw   = (const float*)d_in[20];
  (void)in_sizes; (void)n_in; (void)out_size; (void)ws_size;

  u16* ws = (u16*)d_ws;
  const size_t PSZ = (size_t)ROWS * CDIM;
  const size_t WSZ = (size_t)CDIM * CDIM;
  u16* s0 = ws + 0 * PSZ;
  u16* s1 = ws + 1 * PSZ;
  u16* s2 = ws + 2 * PSZ;
  u16* s3 = ws + 3 * PSZ;
  u16* s4 = ws + 4 * PSZ;
  u16* Wb  = ws + 5 * PSZ;
  u16* Rhb = Wb + 4 * WSZ;
  u16* Rwb = Rhb + 64 * 64;
  u16* qbuf = (u16*)d_out;              // bf16 scratch inside f32 output buffer

  // 1) pool + layernorm (float4-vectorized): Pq->s0, Pk->s1, Pv->s2
  pool_ln_kernel<<<dim3((NOUT + 1) / 2, 8, 2), 256, 0, stream>>>(
      x, xr, cwq, cwk, cwv, gq, lbq, gk, lbk, gv, lbv, s0, s1, s2);

  // 2) weights + rel_pos -> bf16
  wcvt_kernel<<<(4 * CDIM * CDIM / 4 + 255) / 256, 256, 0, stream>>>(wq, wk, wv, wpj, Wb);
  rcvt_kernel<<<16, 256, 0, stream>>>(rph, rpw, Rhb, Rwb);

  // 3) q/k/v projections: q: s0->qbuf, k: s1->s3, v: s2->s4
  dim3 g3((ROWS + 63) / 64, CDIM / 128, 3);
  mgemm3_kernel<<<g3, 256, 0, stream>>>(s0, s1, s2, Wb, bq, bk, bv, qbuf, s3, s4);

  // 4) attention -> s0
  fattn_kernel<<<NKT * 64, 256, 0, stream>>>(qbuf, s3, s4, Rhb, Rwb, s0);

  // 5) output projection -> f32 d_out
  dim3 gp((ROWS + 63) / 64, CDIM / 128);
  mgemm_proj_kernel<<<gp, 256, 0, stream>>>(s0, Wb + 3 * WSZ, bpj, (float*)d_out);
}

// Round 15
// 197.255 us; speedup vs baseline: 1.6364x; 1.0049x over previous
//
#include <hip/hip_runtime.h>

// Problem constants (B=8, T=1, H=56, C=512, nh=8, d=64)
// Inputs: float32. Output: float32. ws intermediates: bf16.
#define NH    8
#define DH    64
#define NTOK  3137      // 56*56+1
#define NOUT  785       // 28*28+1
#define CDIM  512
#define ROWS  6280      // 8*785
#define HO    28
#define HIN   56
#define NKT   13        // ceil(785/64) key tiles
#define RELD  55        // 2*(56//2)-1
#define LOG2E 1.4426950408889634f

typedef unsigned short u16;
typedef __attribute__((ext_vector_type(8))) short bf16x8;   // 8 bf16 = 4 VGPRs
typedef __attribute__((ext_vector_type(4))) float f32x4;    // MFMA C/D

__device__ __forceinline__ float b2f(u16 u) { return __uint_as_float(((unsigned)u) << 16); }
__device__ __forceinline__ u16 f2b(float f) {
  unsigned u = __float_as_uint(f);
  return (u16)((u + 0x7FFFu + ((u >> 16) & 1u)) >> 16);
}

// ---------------------------------------------------------------------------
// Kernel 1: depthwise 3x3 stride-2 pool + LayerNorm(64), float4-vectorized.
// (verified R14)
// ---------------------------------------------------------------------------
__global__ __launch_bounds__(256) void pool_ln_kernel(
    const float* __restrict__ x, const float* __restrict__ xr,
    const float* __restrict__ cwq, const float* __restrict__ cwk, const float* __restrict__ cwv,
    const float* __restrict__ gq, const float* __restrict__ bq,
    const float* __restrict__ gk, const float* __restrict__ bk,
    const float* __restrict__ gv, const float* __restrict__ bv,
    u16* __restrict__ Pq, u16* __restrict__ Pk, u16* __restrict__ Pv)
{
  int tid   = threadIdx.x;
  int n     = blockIdx.x * 2 + (tid >> 7);           // token (wave-uniform half)
  int b     = blockIdx.y;
  int which = blockIdx.z;                            // 0=q(x), 1=k+v(x_ref)
  if (n >= NOUT) return;
  int c4 = tid & 127;
  int c  = c4 * 4;
  int d0 = c & 63;

  const float* src  = which ? xr : x;
  const float* srcb = src + (size_t)b * NTOK * CDIM + c;
  size_t obase = (size_t)(b * NOUT + n) * CDIM + c;

  float4 vq = make_float4(0.f, 0.f, 0.f, 0.f);
  float4 vk = make_float4(0.f, 0.f, 0.f, 0.f);
  const float* cw0 = which ? cwk : cwq;

  if (n == 0) {
    float4 t = *(const float4*)(srcb);
    vq = t; vk = t;
  } else {
    int oy = (n - 1) / HO, ox = (n - 1) % HO;
#pragma unroll
    for (int ky = 0; ky < 3; ++ky) {
      int iy = oy * 2 - 1 + ky;
      if (iy < 0 || iy >= HIN) continue;
#pragma unroll
      for (int kx = 0; kx < 3; ++kx) {
        int ix = ox * 2 - 1 + kx;
        if (ix < 0 || ix >= HIN) continue;
        int tok = 1 + iy * HIN + ix;
        float4 t  = *(const float4*)(srcb + (size_t)tok * CDIM);
        float4 w0 = *(const float4*)(cw0 + (ky * 3 + kx) * DH + d0);
        vq.x += t.x * w0.x; vq.y += t.y * w0.y; vq.z += t.z * w0.z; vq.w += t.w * w0.w;
        if (which) {
          float4 w1 = *(const float4*)(cwv + (ky * 3 + kx) * DH + d0);
          vk.x += t.x * w1.x; vk.y += t.y * w1.y; vk.z += t.z * w1.z; vk.w += t.w * w1.w;
        }
      }
    }
  }

  {
    float s  = vq.x + vq.y + vq.z + vq.w;
    float sq = vq.x * vq.x + vq.y * vq.y + vq.z * vq.z + vq.w * vq.w;
#pragma unroll
    for (int off = 1; off < 16; off <<= 1) {
      s  += __shfl_xor(s, off, 64);
      sq += __shfl_xor(sq, off, 64);
    }
    float mu  = s * (1.f / 64.f);
    float var = sq * (1.f / 64.f) - mu * mu;
    float inv = rsqrtf(var + 1e-5f);
    const float* g  = which ? gk : gq;
    const float* be = which ? bk : bq;
    float4 gg = *(const float4*)(g + d0);
    float4 bb = *(const float4*)(be + d0);
    ushort4 o;
    o.x = f2b((vq.x - mu) * inv * gg.x + bb.x);
    o.y = f2b((vq.y - mu) * inv * gg.y + bb.y);
    o.z = f2b((vq.z - mu) * inv * gg.z + bb.z);
    o.w = f2b((vq.w - mu) * inv * gg.w + bb.w);
    *(ushort4*)(((which ? Pk : Pq)) + obase) = o;
  }
  if (which) {
    float s  = vk.x + vk.y + vk.z + vk.w;
    float sq = vk.x * vk.x + vk.y * vk.y + vk.z * vk.z + vk.w * vk.w;
#pragma unroll
    for (int off = 1; off < 16; off <<= 1) {
      s  += __shfl_xor(s, off, 64);
      sq += __shfl_xor(sq, off, 64);
    }
    float mu  = s * (1.f / 64.f);
    float var = sq * (1.f / 64.f) - mu * mu;
    float inv = rsqrtf(var + 1e-5f);
    float4 gg = *(const float4*)(gv + d0);
    float4 bb = *(const float4*)(bv + d0);
    ushort4 o;
    o.x = f2b((vk.x - mu) * inv * gg.x + bb.x);
    o.y = f2b((vk.y - mu) * inv * gg.y + bb.y);
    o.z = f2b((vk.z - mu) * inv * gg.z + bb.z);
    o.w = f2b((vk.w - mu) * inv * gg.w + bb.w);
    *(ushort4*)(Pv + obase) = o;
  }
}

// ---------------------------------------------------------------------------
// Kernel 2: convert the four 512x512 f32 weight matrices to bf16 (packed).
// ---------------------------------------------------------------------------
__global__ __launch_bounds__(256) void wcvt_kernel(
    const float* __restrict__ W0, const float* __restrict__ W1,
    const float* __restrict__ W2, const float* __restrict__ W3,
    u16* __restrict__ out)
{
  int idx = blockIdx.x * blockDim.x + threadIdx.x;
  const int per = CDIM * CDIM / 4;
  int mat = idx / per, off = (idx - mat * per) * 4;
  const float* src = (mat == 0) ? W0 : (mat == 1) ? W1 : (mat == 2) ? W2 : W3;
  float4 v = *(const float4*)(src + off);
  ushort4 o;
  o.x = f2b(v.x); o.y = f2b(v.y); o.z = f2b(v.z); o.w = f2b(v.w);
  *(ushort4*)(out + (size_t)mat * (CDIM * CDIM) + off) = o;
}

// ---------------------------------------------------------------------------
// Kernel 3: rel_pos f32 (55x64) -> bf16 padded [64][64], PRE-SCALED by log2e
// (softmax runs in exp2 domain).
// ---------------------------------------------------------------------------
__global__ __launch_bounds__(256) void rcvt_kernel(
    const float* __restrict__ rph, const float* __restrict__ rpw,
    u16* __restrict__ Rhb, u16* __restrict__ Rwb)
{
  int idx = blockIdx.x * blockDim.x + threadIdx.x;
  if (idx >= 64 * 64) return;
  int r = idx >> 6, d = idx & 63;
  Rhb[idx] = (r < RELD) ? f2b(rph[r * DH + d] * LOG2E) : 0;
  Rwb[idx] = (r < RELD) ? f2b(rpw[r * DH + d] * LOG2E) : 0;
}

// ---------------------------------------------------------------------------
// Kernel 4a: batched MFMA GEMM for q/k/v. Tile 64x128 (wave 32x64).
// ---------------------------------------------------------------------------
__global__ __launch_bounds__(256) void mgemm3_kernel(
    const u16* __restrict__ Xq, const u16* __restrict__ Xk, const u16* __restrict__ Xv,
    const u16* __restrict__ Wb, const float* __restrict__ bq,
    const float* __restrict__ bk, const float* __restrict__ bv,
    u16* __restrict__ Yq, u16* __restrict__ Yk, u16* __restrict__ Yv)
{
  int z = blockIdx.z;
  const u16* X = (z == 0) ? Xq : (z == 1) ? Xk : Xv;
  const u16* W = Wb + (size_t)z * CDIM * CDIM;
  const float* bias = (z == 0) ? bq : (z == 1) ? bk : bv;
  u16* Y = (z == 0) ? Yq : (z == 1) ? Yk : Yv;

  int tid = threadIdx.x;
  int w = tid >> 6, lane = tid & 63, l15 = lane & 15, lg = lane >> 4;
  int m0 = blockIdx.x * 64 + (w >> 1) * 32;
  int n0 = blockIdx.y * 128 + (w & 1) * 64;

  f32x4 acc[2][4] = {};
  float bs[4];
#pragma unroll
  for (int nf = 0; nf < 4; ++nf) bs[nf] = bias[n0 + nf * 16 + l15];

  for (int k0 = 0; k0 < CDIM; k0 += 32) {
    bf16x8 a[2], b[4];
#pragma unroll
    for (int mf = 0; mf < 2; ++mf) {
      int r = m0 + mf * 16 + l15;
      if (r > ROWS - 1) r = ROWS - 1;
      a[mf] = *(const bf16x8*)(X + (size_t)r * CDIM + k0 + lg * 8);
    }
#pragma unroll
    for (int nf = 0; nf < 4; ++nf) {
      int co = n0 + nf * 16 + l15;
      b[nf] = *(const bf16x8*)(W + (size_t)co * CDIM + k0 + lg * 8);
    }
#pragma unroll
    for (int mf = 0; mf < 2; ++mf)
#pragma unroll
      for (int nf = 0; nf < 4; ++nf)
        acc[mf][nf] = __builtin_amdgcn_mfma_f32_16x16x32_bf16(a[mf], b[nf], acc[mf][nf], 0, 0, 0);
  }

#pragma unroll
  for (int mf = 0; mf < 2; ++mf) {
#pragma unroll
    for (int j = 0; j < 4; ++j) {
      int r = m0 + mf * 16 + lg * 4 + j;
      if (r >= ROWS) continue;
      int bb = r / NOUT, n = r % NOUT;
#pragma unroll
      for (int nf = 0; nf < 4; ++nf) {
        int co = n0 + nf * 16 + l15;
        float v = acc[mf][nf][j] + bs[nf];
        Y[(((size_t)bb * NH + (co >> 6)) * NOUT + n) * DH + (co & 63)] = f2b(v);
      }
    }
  }
}

// ---------------------------------------------------------------------------
// Kernel 4b: proj MFMA GEMM, 64x128 tile -> f32 row-major d_out.
// ---------------------------------------------------------------------------
__global__ __launch_bounds__(256) void mgemm_proj_kernel(
    const u16* __restrict__ X, const u16* __restrict__ Wb, const float* __restrict__ bias,
    float* __restrict__ Y)
{
  int tid = threadIdx.x;
  int w = tid >> 6, lane = tid & 63, l15 = lane & 15, lg = lane >> 4;
  int m0 = blockIdx.x * 64 + (w >> 1) * 32;
  int n0 = blockIdx.y * 128 + (w & 1) * 64;

  f32x4 acc[2][4] = {};
  float bs[4];
#pragma unroll
  for (int nf = 0; nf < 4; ++nf) bs[nf] = bias[n0 + nf * 16 + l15];

  for (int k0 = 0; k0 < CDIM; k0 += 32) {
    bf16x8 a[2], b[4];
#pragma unroll
    for (int mf = 0; mf < 2; ++mf) {
      int r = m0 + mf * 16 + l15;
      if (r > ROWS - 1) r = ROWS - 1;
      a[mf] = *(const bf16x8*)(X + (size_t)r * CDIM + k0 + lg * 8);
    }
#pragma unroll
    for (int nf = 0; nf < 4; ++nf) {
      int co = n0 + nf * 16 + l15;
      b[nf] = *(const bf16x8*)(Wb + (size_t)co * CDIM + k0 + lg * 8);
    }
#pragma unroll
    for (int mf = 0; mf < 2; ++mf)
#pragma unroll
      for (int nf = 0; nf < 4; ++nf)
        acc[mf][nf] = __builtin_amdgcn_mfma_f32_16x16x32_bf16(a[mf], b[nf], acc[mf][nf], 0, 0, 0);
  }

#pragma unroll
  for (int mf = 0; mf < 2; ++mf) {
#pragma unroll
    for (int j = 0; j < 4; ++j) {
      int r = m0 + mf * 16 + lg * 4 + j;
      if (r >= ROWS) continue;
#pragma unroll
      for (int nf = 0; nf < 4; ++nf) {
        int co = n0 + nf * 16 + l15;
        Y[(size_t)r * CDIM + co] = acc[mf][nf][j] + bs[nf];
      }
    }
  }
}

// ---------------------------------------------------------------------------
// Kernel 5: flash-style MFMA attention.
// R14 structure + exp2-domain softmax, deferred l-sum reduce (epilogue-only),
// skip-rescale when tile max doesn't exceed running max.
// ---------------------------------------------------------------------------
__global__ __launch_bounds__(256, 4) void fattn_kernel(
    const u16* __restrict__ Q, const u16* __restrict__ K, const u16* __restrict__ V,
    const u16* __restrict__ Rhb, const u16* __restrict__ Rwb,
    u16* __restrict__ O)
{
  __shared__ u16 Vs[2][64][64];     // [buf][d][k] XOR-swizzled      16384 B
  __shared__ u16 Ps[4][16][72];     // per-wave P bounce              9216 B
  __shared__ u16 relh[64][RELD];    // G_h[q][r]  (log2e-scaled)      7040 B
  __shared__ u16 relw[64][RELD];    //                                7040 B

  int bid = blockIdx.x;
  int nbid = (bid & 7) * 104 + (bid >> 3);
  int bh = nbid / NKT, qt = nbid % NKT;

  int tid = threadIdx.x;
  int w = tid >> 6, lane = tid & 63, l15 = lane & 15, lg = lane >> 4;
  size_t base = (size_t)bh * NOUT * DH;
  int q0 = qt * 64;

  int vkey_l = tid & 63;
  int vd0 = (tid >> 6) * 16;

  // ---- Q A-fragments direct from global ----
  int qrow_qi = min(q0 + w * 16 + l15, NOUT - 1);
  const u16* qp = Q + base + (size_t)qrow_qi * DH + lg * 8;
  bf16x8 qa0 = *(const bf16x8*)(qp);
  bf16x8 qa1 = *(const bf16x8*)(qp + 32);

  // ---- prologue V stage: tile 0 -> Vs[0] ----
  {
    int key = min(vkey_l, NOUT - 1);
    const u16* vp = V + base + (size_t)key * DH + vd0;
    bf16x8 v0 = *(const bf16x8*)(vp);
    bf16x8 v1 = *(const bf16x8*)(vp + 8);
#pragma unroll
    for (int i = 0; i < 8; ++i) {
      int d = vd0 + i;
      Vs[0][d][((((vkey_l >> 3) ^ (d & 7)) << 3) | (vkey_l & 7))] = (u16)v0[i];
    }
#pragma unroll
    for (int i = 0; i < 8; ++i) {
      int d = vd0 + 8 + i;
      Vs[0][d][((((vkey_l >> 3) ^ (d & 7)) << 3) | (vkey_l & 7))] = (u16)v1[i];
    }
  }

  // ---- rel-pos tables via MFMA (wave-private rows, log2e-scaled) ----
#pragma unroll
  for (int nf = 0; nf < 4; ++nf) {
    int rr = nf * 16 + l15;
    const u16* hp = Rhb + rr * 64 + lg * 8;
    bf16x8 hb0 = *(const bf16x8*)(hp);
    bf16x8 hb1 = *(const bf16x8*)(hp + 32);
    f32x4 ah = {};
    ah = __builtin_amdgcn_mfma_f32_16x16x32_bf16(qa0, hb0, ah, 0, 0, 0);
    ah = __builtin_amdgcn_mfma_f32_16x16x32_bf16(qa1, hb1, ah, 0, 0, 0);
    const u16* wp = Rwb + rr * 64 + lg * 8;
    bf16x8 wb0 = *(const bf16x8*)(wp);
    bf16x8 wb1 = *(const bf16x8*)(wp + 32);
    f32x4 aw = {};
    aw = __builtin_amdgcn_mfma_f32_16x16x32_bf16(qa0, wb0, aw, 0, 0, 0);
    aw = __builtin_amdgcn_mfma_f32_16x16x32_bf16(qa1, wb1, aw, 0, 0, 0);
    if (rr < RELD) {
#pragma unroll
      for (int j = 0; j < 4; ++j) {
        relh[w * 16 + lg * 4 + j][rr] = f2b(ah[j]);
        relw[w * 16 + lg * 4 + j][rr] = f2b(aw[j]);
      }
    }
  }

  // ---- per-j query geometry ----
  int qy_j[4], qx_j[4];
  bool qv_j[4];
#pragma unroll
  for (int j = 0; j < 4; ++j) {
    int qi = q0 + w * 16 + lg * 4 + j;
    qv_j[j] = (qi >= 1);
    int qm1 = qi - 1;
    qy_j[j] = qm1 / HO;
    qx_j[j] = qm1 % HO;
  }

  // ---- incremental key geometry per sub ----
  int kyr[4], kxr[4];
#pragma unroll
  for (int sub = 0; sub < 4; ++sub) {
    int km1 = sub * 16 + l15 - 1;   // -1 only for (sub=0,l15=0): unused (key<1)
    kyr[sub] = km1 / HO;
    kxr[sub] = km1 % HO;
  }

  f32x4 o0 = {}, o1 = {}, o2 = {}, o3 = {};
  float mrow[4], lrow[4];
#pragma unroll
  for (int j = 0; j < 4; ++j) { mrow[j] = -1e30f; lrow[j] = 0.f; }

  const float QKSCALE = 0.125f * LOG2E;

  for (int t = 0; t < NKT; ++t) {
    int k0 = t * 64;
    int cur = t & 1;
    __syncthreads();   // Vs[cur] fully staged; prev tile's PV reads done

    // ---- issue next V tile's global loads FIRST ----
    bf16x8 nv0, nv1;
    bool have_next = (t + 1 < NKT);
    if (have_next) {
      int key = min(k0 + 64 + vkey_l, NOUT - 1);
      const u16* vp = V + base + (size_t)key * DH + vd0;
      nv0 = *(const bf16x8*)(vp);
      nv1 = *(const bf16x8*)(vp + 8);
    }

    // ---- K fragment loads ----
    bf16x8 kb[4][2];
#pragma unroll
    for (int sub = 0; sub < 4; ++sub) {
      int key = k0 + sub * 16 + l15;
      int keff = min(key, NOUT - 1);
      const u16* kp = K + base + (size_t)keff * DH + lg * 8;
      kb[sub][0] = *(const bf16x8*)(kp);
      kb[sub][1] = *(const bf16x8*)(kp + 32);
    }

    // ---- S = scale*Q.K^T + bias   (log2 domain) ----
    f32x4 s[4];
#pragma unroll
    for (int sub = 0; sub < 4; ++sub) {
      int key = k0 + sub * 16 + l15;
      f32x4 acc = {};
      acc = __builtin_amdgcn_mfma_f32_16x16x32_bf16(qa0, kb[sub][0], acc, 0, 0, 0);
      acc = __builtin_amdgcn_mfma_f32_16x16x32_bf16(qa1, kb[sub][1], acc, 0, 0, 0);
      bool kv = key < NOUT;
      int ky = kyr[sub], kx = kxr[sub];
#pragma unroll
      for (int j = 0; j < 4; ++j) {
        float v = acc[j] * QKSCALE;
        if (key >= 1 && kv && qv_j[j]) {
          int ql = w * 16 + lg * 4 + j;
          v += b2f(relh[ql][qy_j[j] - ky + 27]) + b2f(relw[ql][qx_j[j] - kx + 27]);
        }
        if (!kv) v = -1e30f;
        s[sub][j] = v;
      }
    }

    // ---- advance key geometry (+64 keys = +2 rows +8 cols, carry) ----
#pragma unroll
    for (int sub = 0; sub < 4; ++sub) {
      kxr[sub] += 8; kyr[sub] += 2;
      if (kxr[sub] >= HO) { kxr[sub] -= HO; kyr[sub] += 1; }
    }

    // ---- write next V tile into idle buffer (no barrier needed) ----
    if (have_next) {
#pragma unroll
      for (int i = 0; i < 8; ++i) {
        int d = vd0 + i;
        Vs[cur ^ 1][d][((((vkey_l >> 3) ^ (d & 7)) << 3) | (vkey_l & 7))] = (u16)nv0[i];
      }
#pragma unroll
      for (int i = 0; i < 8; ++i) {
        int d = vd0 + 8 + i;
        Vs[cur ^ 1][d][((((vkey_l >> 3) ^ (d & 7)) << 3) | (vkey_l & 7))] = (u16)nv1[i];
      }
    }

    // ---- online softmax (exp2 domain; l-sum kept as per-lane partials) ----
#pragma unroll
    for (int j = 0; j < 4; ++j) {
      float lm = fmaxf(fmaxf(s[0][j], s[1][j]), fmaxf(s[2][j], s[3][j]));
      lm = fmaxf(lm, __shfl_xor(lm, 1));
      lm = fmaxf(lm, __shfl_xor(lm, 2));
      lm = fmaxf(lm, __shfl_xor(lm, 4));
      lm = fmaxf(lm, __shfl_xor(lm, 8));
      if (lm > mrow[j]) {            // rescale only when the max grows
        float a = exp2f(mrow[j] - lm);
        mrow[j] = lm;
        o0[j] *= a; o1[j] *= a; o2[j] *= a; o3[j] *= a;
        lrow[j] *= a;
      }
      float ps = 0.f;
#pragma unroll
      for (int sub = 0; sub < 4; ++sub) {
        float pv = exp2f(s[sub][j] - mrow[j]);
        s[sub][j] = pv;
        ps += pv;
      }
      lrow[j] += ps;                 // per-lane partial; reduced in epilogue
    }

    // ---- bounce P (wave-private) ----
#pragma unroll
    for (int j = 0; j < 4; ++j) {
      Ps[w][lg * 4 + j][ 0 + l15] = f2b(s[0][j]);
      Ps[w][lg * 4 + j][16 + l15] = f2b(s[1][j]);
      Ps[w][lg * 4 + j][32 + l15] = f2b(s[2][j]);
      Ps[w][lg * 4 + j][48 + l15] = f2b(s[3][j]);
    }

    // ---- O += P.V from Vs[cur] ----
    bf16x8 pa0 = *(const bf16x8*)&Ps[w][l15][lg * 8];
    bf16x8 pa1 = *(const bf16x8*)&Ps[w][l15][32 + lg * 8];
    {
      int r = 0 + l15;
      bf16x8 vb0 = *(const bf16x8*)&Vs[cur][r][((lg ^ (r & 7)) << 3)];
      bf16x8 vb1 = *(const bf16x8*)&Vs[cur][r][(((4 + lg) ^ (r & 7)) << 3)];
      o0 = __builtin_amdgcn_mfma_f32_16x16x32_bf16(pa0, vb0, o0, 0, 0, 0);
      o0 = __builtin_amdgcn_mfma_f32_16x16x32_bf16(pa1, vb1, o0, 0, 0, 0);
    }
    {
      int r = 16 + l15;
      bf16x8 vb0 = *(const bf16x8*)&Vs[cur][r][((lg ^ (r & 7)) << 3)];
      bf16x8 vb1 = *(const bf16x8*)&Vs[cur][r][(((4 + lg) ^ (r & 7)) << 3)];
      o1 = __builtin_amdgcn_mfma_f32_16x16x32_bf16(pa0, vb0, o1, 0, 0, 0);
      o1 = __builtin_amdgcn_mfma_f32_16x16x32_bf16(pa1, vb1, o1, 0, 0, 0);
    }
    {
      int r = 32 + l15;
      bf16x8 vb0 = *(const bf16x8*)&Vs[cur][r][((lg ^ (r & 7)) << 3)];
      bf16x8 vb1 = *(const bf16x8*)&Vs[cur][r][(((4 + lg) ^ (r & 7)) << 3)];
      o2 = __builtin_amdgcn_mfma_f32_16x16x32_bf16(pa0, vb0, o2, 0, 0, 0);
      o2 = __builtin_amdgcn_mfma_f32_16x16x32_bf16(pa1, vb1, o2, 0, 0, 0);
    }
    {
      int r = 48 + l15;
      bf16x8 vb0 = *(const bf16x8*)&Vs[cur][r][((lg ^ (r & 7)) << 3)];
      bf16x8 vb1 = *(const bf16x8*)&Vs[cur][r][(((4 + lg) ^ (r & 7)) << 3)];
      o3 = __builtin_amdgcn_mfma_f32_16x16x32_bf16(pa0, vb0, o3, 0, 0, 0);
      o3 = __builtin_amdgcn_mfma_f32_16x16x32_bf16(pa1, vb1, o3, 0, 0, 0);
    }
  }

  // ---- epilogue: reduce l partials, normalize, residual, store ----
  int b = bh >> 3, h = bh & 7;
#pragma unroll
  for (int j = 0; j < 4; ++j) {
    int ql = w * 16 + lg * 4 + j;
    int qi = q0 + ql;
    float l = lrow[j];
    l += __shfl_xor(l, 1);
    l += __shfl_xor(l, 2);
    l += __shfl_xor(l, 4);
    l += __shfl_xor(l, 8);
    if (qi >= NOUT) continue;
    float inv = 1.f / l;
    float v0 = o0[j] * inv, v1 = o1[j] * inv, v2 = o2[j] * inv, v3 = o3[j] * inv;
    if (qi > 0) {
      const u16* qp2 = Q + base + (size_t)qi * DH;
      v0 += b2f(qp2[ 0 + l15]);
      v1 += b2f(qp2[16 + l15]);
      v2 += b2f(qp2[32 + l15]);
      v3 += b2f(qp2[48 + l15]);
    }
    size_t ob = ((size_t)b * NOUT + qi) * CDIM + h * DH;
    O[ob +  0 + l15] = f2b(v0);
    O[ob + 16 + l15] = f2b(v1);
    O[ob + 32 + l15] = f2b(v2);
    O[ob + 48 + l15] = f2b(v3);
  }
}

// ---------------------------------------------------------------------------
// ws layout (u16): s0..s4 (5 x PSZ), Wb (4 x WSZ), Rhb/Rwb (2 x 4096). ~34 MB.
// Schedule: pool: Pq->s0, Pk->s1, Pv->s2
//           mgemm3: s0->qbuf(Q), s1->s3(K), s2->s4(V)   [disjoint in/out]
//           fattn:  (qbuf,s3,s4) -> s0
//           proj:   s0 -> d_out (f32, overwrites qbuf; Q dead)
// ---------------------------------------------------------------------------
extern "C" void kernel_launch(void* const* d_in, const int* in_sizes, int n_in,
                              void* d_out, int out_size, void* d_ws, size_t ws_size,
                              hipStream_t stream) {
  const float* x     = (const float*)d_in[0];
  const float* xr    = (const float*)d_in[1];
  const float* wq    = (const float*)d_in[2];
  const float* bq    = (const float*)d_in[3];
  const float* wk    = (const float*)d_in[4];
  const float* bk    = (const float*)d_in[5];
  const float* wv    = (const float*)d_in[6];
  const float* bv    = (const float*)d_in[7];
  const float* wpj   = (const float*)d_in[8];
  const float* bpj   = (const float*)d_in[9];
  const float* cwq   = (const float*)d_in[10];
  const float* cwk   = (const float*)d_in[11];
  const float* cwv   = (const float*)d_in[12];
  const float* gq    = (const float*)d_in[13];
  const float* lbq   = (const float*)d_in[14];
  const float* gk    = (const float*)d_in[15];
  const float* lbk   = (const float*)d_in[16];
  const float* gv    = (const float*)d_in[17];
  const float* lbv   = (const float*)d_in[18];
  const float* rph   = (const float*)d_in[19];
  const float* rpw   = (const float*)d_in[20];
  (void)in_sizes; (void)n_in; (void)out_size; (void)ws_size;

  u16* ws = (u16*)d_ws;
  const size_t PSZ = (size_t)ROWS * CDIM;
  const size_t WSZ = (size_t)CDIM * CDIM;
  u16* s0 = ws + 0 * PSZ;
  u16* s1 = ws + 1 * PSZ;
  u16* s2 = ws + 2 * PSZ;
  u16* s3 = ws + 3 * PSZ;
  u16* s4 = ws + 4 * PSZ;
  u16* Wb  = ws + 5 * PSZ;
  u16* Rhb = Wb + 4 * WSZ;
  u16* Rwb = Rhb + 64 * 64;
  u16* qbuf = (u16*)d_out;              // bf16 scratch inside f32 output buffer

  // 1) pool + layernorm (float4-vectorized): Pq->s0, Pk->s1, Pv->s2
  pool_ln_kernel<<<dim3((NOUT + 1) / 2, 8, 2), 256, 0, stream>>>(
      x, xr, cwq, cwk, cwv, gq, lbq, gk, lbk, gv, lbv, s0, s1, s2);

  // 2) weights + rel_pos -> bf16 (rel_pos pre-scaled by log2e)
  wcvt_kernel<<<(4 * CDIM * CDIM / 4 + 255) / 256, 256, 0, stream>>>(wq, wk, wv, wpj, Wb);
  rcvt_kernel<<<16, 256, 0, stream>>>(rph, rpw, Rhb, Rwb);

  // 3) q/k/v projections: q: s0->qbuf, k: s1->s3, v: s2->s4
  dim3 g3((ROWS + 63) / 64, CDIM / 128, 3);
  mgemm3_kernel<<<g3, 256, 0, stream>>>(s0, s1, s2, Wb, bq, bk, bv, qbuf, s3, s4);

  // 4) attention -> s0
  fattn_kernel<<<NKT * 64, 256, 0, stream>>>(qbuf, s3, s4, Rhb, Rwb, s0);

  // 5) output projection -> f32 d_out
  dim3 gp((ROWS + 63) / 64, CDIM / 128);
  mgemm_proj_kernel<<<gp, 256, 0, stream>>>(s0, Wb + 3 * WSZ, bpj, (float*)d_out);
}